// Round 6
// baseline (909.445 us; speedup 1.0000x reference)
//
#include <hip/hip_runtime.h>
#include <hip/hip_bf16.h>

#define VROW 368      // agg row: [w1s 192 | w2v 48 | cross 48 | sc 64 | sc2 16]
#define WST  184      // wbuf row stride in f16 (176 + 8 pad)

typedef __attribute__((ext_vector_type(8))) short bf16x8;
typedef __attribute__((ext_vector_type(4))) float f32x4;

__device__ inline ushort f2bf(float f){
  union { __hip_bfloat16 b; ushort u; } v;
  v.b = __float2bfloat16(f);
  return v.u;
}

// ---------- K1: node transforms (64 nodes / block) ----------
__global__ __launch_bounds__(256) void k_node(
  const float* __restrict__ ni,
  const float* __restrict__ wss, const float* __restrict__ wsv,
  const float* __restrict__ wds, const float* __restrict__ wdv,
  float* __restrict__ xs_s, float* __restrict__ xs_d,
  float* __restrict__ xv_s, float* __restrict__ xv_d, int N)
{
  __shared__ float sW0[64*64], sW1[64*64];
  __shared__ float sV0[256], sV1[256];
  __shared__ float sRow[4][112];
  int t = threadIdx.x, wid = t>>6, lane = t&63;
  for(int i=t;i<4096;i+=256){ sW0[i]=wss[i]; sW1[i]=wds[i]; }
  if(t<256){ sV0[t]=wsv[t]; sV1[t]=wdv[t]; }
  __syncthreads();
  for(int itn=0; itn<16; ++itn){
    int node = blockIdx.x*64 + itn*4 + wid;
    if(node>=N) continue;
    const float* row = ni + (size_t)node*112;
    if(lane<56) ((float2*)sRow[wid])[lane] = ((const float2*)row)[lane];
    float* r = sRow[wid];
    float a0=0.f, a1=0.f;
    #pragma unroll 8
    for(int k=0;k<64;k++){ float x=r[k]; a0+=x*sW0[k*64+lane]; a1+=x*sW1[k*64+lane]; }
    xs_s[(size_t)node*64+lane]=a0; xs_d[(size_t)node*64+lane]=a1;
    if(lane<48){
      int e_=lane/3, d_=lane-e_*3; float b0=0.f, b1=0.f;
      #pragma unroll
      for(int c=0;c<16;c++){ float x=r[64+c*3+d_]; b0+=x*sV0[c*16+e_]; b1+=x*sV1[c*16+e_]; }
      xv_s[(size_t)node*48+lane]=b0; xv_d[(size_t)node*48+lane]=b1;
    }
  }
}

// ---------- CSR build ----------
__global__ void k_deg(const int* __restrict__ edst, int* __restrict__ deg, int E){
  int e = blockIdx.x*256 + threadIdx.x;
  if(e<E) atomicAdd(&deg[edst[e]], 1);
}

__global__ __launch_bounds__(256) void k_scan(
  const int* __restrict__ deg, int* __restrict__ offs, int* __restrict__ cur, int N)
{
  __shared__ int sb[256];
  __shared__ int srun;
  int t = threadIdx.x;
  if(t==0) srun = 0;
  __syncthreads();
  for(int base=0; base<N; base+=256){
    int i = base + t;
    int x = (i<N) ? deg[i] : 0;
    sb[t] = x;
    __syncthreads();
    int v = x;
    #pragma unroll
    for(int o=1;o<256;o<<=1){
      int u = (t>=o) ? sb[t-o] : 0;
      __syncthreads();
      v += u; sb[t] = v;
      __syncthreads();
    }
    int run = srun;
    if(i<N){ int ex = run + v - x; offs[i]=ex; cur[i]=ex; }
    __syncthreads();
    if(t==255) srun = run + v;
    __syncthreads();
  }
  if(t==0) offs[N] = srun;
}

// fill: CSR-ordered src + edge_attr, plus e->slot map for k_mlp scatter
__global__ void k_fill(const int* __restrict__ esrc, const int* __restrict__ edst,
                       const float* __restrict__ eattr,
                       int* __restrict__ cur, int* __restrict__ pos_of,
                       int* __restrict__ srcC, float4* __restrict__ eaC, int E){
  int e = blockIdx.x*256 + threadIdx.x;
  if(e<E){
    int p = atomicAdd(&cur[edst[e]], 1);
    pos_of[e] = p;
    srcC[p] = esrc[e];
    eaC[p] = *(const float4*)&eattr[(size_t)e*4];
  }
}

// ---------- K2: radial MLP (MFMA), writes wbuf rows at CSR slots ----------
__global__ __launch_bounds__(256) void k_mlp(
  const float* __restrict__ escal,
  const float* __restrict__ w1, const float* __restrict__ b1,
  const float* __restrict__ w2, const float* __restrict__ b2,
  const int* __restrict__ pos_of,
  _Float16* __restrict__ wbuf, int E)
{
  __shared__ __align__(16) ushort sW1t[64*136];
  __shared__ __align__(16) ushort sW2t[176*72];
  __shared__ __align__(16) ushort ubuf[4][16*WST];
  int t = threadIdx.x, wid = t>>6, lane = t&63;
  int r16 = lane&15, g = lane>>4;

  for(int i=t;i<128*64;i+=256){ int k=i>>6, n=i&63; sW1t[n*136+k]=f2bf(w1[i]); }
  for(int i=t;i<64*176;i+=256){ int k=i/176, n=i-k*176; sW2t[n*72+k]=f2bf(w2[i]); }
  __syncthreads();

  float b1v[4], b2v[11];
  #pragma unroll
  for(int nt=0;nt<4;nt++) b1v[nt]=b1[nt*16+r16];
  #pragma unroll
  for(int s=0;s<11;s++) b2v[s]=b2[s*16+r16];

  ushort* ub = ubuf[wid];
  _Float16* wsb = (_Float16*)ub;

  int ntiles = (E+15)>>4;
  int nw = gridDim.x*4;

  for(int wt = blockIdx.x*4+wid; wt < ntiles; wt += nw){
    int ebase = wt*16;
    int erow = ebase + r16; if(erow >= E) erow = E-1;

    f32x4 acc[4];
    #pragma unroll
    for(int nt=0;nt<4;nt++) acc[nt]=(f32x4){0,0,0,0};
    #pragma unroll
    for(int ks=0;ks<4;ks++){
      const float* p = escal + (size_t)erow*128 + ks*32 + g*8;
      float4 va = *(const float4*)p;
      float4 vb = *(const float4*)(p+4);
      bf16x8 af;
      af[0]=(short)f2bf(va.x); af[1]=(short)f2bf(va.y);
      af[2]=(short)f2bf(va.z); af[3]=(short)f2bf(va.w);
      af[4]=(short)f2bf(vb.x); af[5]=(short)f2bf(vb.y);
      af[6]=(short)f2bf(vb.z); af[7]=(short)f2bf(vb.w);
      #pragma unroll
      for(int nt=0;nt<4;nt++){
        bf16x8 bf = *(const bf16x8*)&sW1t[(nt*16+r16)*136 + ks*32 + g*8];
        acc[nt] = __builtin_amdgcn_mfma_f32_16x16x32_bf16(af,bf,acc[nt],0,0,0);
      }
    }

    #pragma unroll
    for(int nt=0;nt<4;nt++)
      #pragma unroll
      for(int q=0;q<4;q++) acc[nt][q] += b1v[nt];
    #pragma unroll
    for(int q=0;q<4;q++){
      float s = acc[0][q]+acc[1][q]+acc[2][q]+acc[3][q];
      float ss = acc[0][q]*acc[0][q]+acc[1][q]*acc[1][q]+acc[2][q]*acc[2][q]+acc[3][q]*acc[3][q];
      #pragma unroll
      for(int o=1;o<16;o<<=1){ s += __shfl_xor(s,o); ss += __shfl_xor(ss,o); }
      float m = s*(1.f/64.f);
      float var = ss*(1.f/64.f) - m*m;
      float inv = rsqrtf(var + 1e-5f);
      int rr = g*4+q;
      #pragma unroll
      for(int nt=0;nt<4;nt++){
        float xn = (acc[nt][q]-m)*inv;
        float h = xn/(1.f+__expf(-xn));
        ub[rr*72 + nt*16 + r16] = f2bf(h);
      }
    }

    bf16x8 af2[2];
    af2[0] = *(const bf16x8*)&ub[r16*72 + 0*32 + g*8];
    af2[1] = *(const bf16x8*)&ub[r16*72 + 1*32 + g*8];
    f32x4 c2[11];
    #pragma unroll
    for(int s=0;s<11;s++) c2[s]=(f32x4){0,0,0,0};
    #pragma unroll
    for(int ks=0;ks<2;ks++){
      #pragma unroll
      for(int s=0;s<11;s++){
        bf16x8 bf = *(const bf16x8*)&sW2t[(s*16+r16)*72 + ks*32 + g*8];
        c2[s] = __builtin_amdgcn_mfma_f32_16x16x32_bf16(af2[ks],bf,c2[s],0,0,0);
      }
    }
    #pragma unroll
    for(int s=0;s<11;s++){
      int col = s*16 + r16;
      #pragma unroll
      for(int q=0;q<4;q++){
        wsb[(g*4+q)*WST + col] = (_Float16)(c2[s][q] + b2v[s]);
      }
    }
    // scatter rows to CSR slots
    int pv = 0;
    if(lane<16 && ebase+lane < E) pv = pos_of[ebase+lane];
    int rows = E - ebase; if(rows > 16) rows = 16;
    const float4* srcv = (const float4*)ub;
    int tot4 = rows*23;   // 23 float4 per row (WST/8)
    for(int i=lane; i<tot4; i+=64){
      int r = i/23, c = i - 23*r;
      int pos = __shfl(pv, r);
      ((float4*)(wbuf + (size_t)pos*WST))[c] = srcv[i];
    }
  }
}

// ---------- K3: fused geometric + softmax + aggregation (wave per node) ----------
__global__ __launch_bounds__(256) void k_fuse(
  const int* __restrict__ offs, const int* __restrict__ srcC,
  const float4* __restrict__ eaC, const _Float16* __restrict__ wbuf,
  const float* __restrict__ adot,
  const float* __restrict__ xs_s, const float* __restrict__ xs_d,
  const float* __restrict__ xv_s, const float* __restrict__ xv_d,
  float* __restrict__ alphaC, float* __restrict__ agg, int N)
{
  __shared__ float sAdot[80];
  __shared__ uchar2 sT3[192];
  __shared__ float sV[4][48];
  __shared__ float sWS1[4][64];
  __shared__ float sP[4][80];
  int t = threadIdx.x, wid = t>>6, lane = t&63;
  if(t<80) sAdot[t]=adot[t];
  for(int i=t;i<192;i+=256){ int r=i/3; sT3[i]=make_uchar2((unsigned char)r,(unsigned char)(i-3*r)); }
  __syncthreads();

  float* V = sV[wid];
  float* WS1 = sWS1[wid];
  float* P = sP[wid];
  const float inv_s3 = 0.5773502691896258f, inv_s2 = 0.7071067811865475f;

  // static per-lane head indices (sources always in 0..7)
  int hSC  = lane/10;                    // region sc: j=288+lane
  int hSC2 = (64+(lane&15))/10;          // region sc2: j=352+(lane&15)
  int hW10 = lane/36;                    // j=lane
  int hW11 = (64+lane)/36;               // j=64+lane
  int hW12 = (128+lane)/36;              // j=128+lane
  int l3 = lane/3;
  int hW2  = (64+l3)/12;                 // j=192+lane -> ch=64+lane/3
  int hX   = (80+l3)/12;                 // j=240+lane -> ch=80+lane/3

  int nw4 = gridDim.x*4;
  for(int n = blockIdx.x*4+wid; n < N; n += nw4){
    int s0 = offs[n], s1 = offs[n+1];
    float sd  = xs_d[(size_t)n*64+lane];
    float vdl = (lane<48) ? xv_d[(size_t)n*48+lane] : 0.f;

    // ---- pass A: alpha per edge + per-head running max (lane<8) ----
    float mx = -1e30f;
    for(int b=s0; b<s1; ++b){
      int src = srcC[b];
      float4 ea = eaC[b];
      const _Float16* wr = wbuf + (size_t)b*WST;
      float S = xs_s[(size_t)src*64+lane] + sd;
      if(lane<48) V[lane] = xv_s[(size_t)src*48+lane] + vdl;
      float w0 = (float)wr[lane];
      float sc = w0*S*ea.x;
      float sg = 1.f/(1.f+__expf(-sc));
      P[lane] = sc*(0.2f + 0.8f*sg)*sAdot[lane];
      if(lane<16){
        float vd3 = V[lane*3]*ea.y + V[lane*3+1]*ea.z + V[lane*3+2]*ea.w;
        float sc2 = (float)wr[144+lane]*vd3*inv_s3;
        float sg2 = 1.f/(1.f+__expf(-sc2));
        P[64+lane] = sc2*(0.2f + 0.8f*sg2)*sAdot[64+lane];
      }
      if(lane<8){
        float a = P[lane*10];
        #pragma unroll
        for(int c=1;c<10;c++) a += P[lane*10+c];
        alphaC[(size_t)b*8+lane] = a;
        mx = fmaxf(mx, a);
      }
    }

    // ---- pass B: exp weights, weighted accumulate, den ----
    float den = 0.f;
    float accW1_0=0.f, accW1_1=0.f, accW1_2=0.f;
    float accW2=0.f, accX=0.f, accSC=0.f, accSC2=0.f;
    for(int b=s0; b<s1; ++b){
      int src = srcC[b];
      float4 ea = eaC[b];
      const _Float16* wr = wbuf + (size_t)b*WST;
      float S = xs_s[(size_t)src*64+lane] + sd;
      float Vl = 0.f;
      if(lane<48){ Vl = xv_s[(size_t)src*48+lane] + vdl; V[lane] = Vl; }
      float w0 = (float)wr[lane];
      float w1v = (float)wr[64+lane];
      WS1[lane] = w1v*S;
      float ev = 0.f;
      if(lane<8){ ev = __expf(alphaC[(size_t)b*8+lane] - mx); den += ev; }
      // broadcast attention weights (all lanes execute; sources 0..7 active)
      float evSC  = __shfl(ev, hSC);
      float evSC2 = __shfl(ev, hSC2);
      float evW10 = __shfl(ev, hW10);
      float evW11 = __shfl(ev, hW11);
      float evW12 = __shfl(ev, hW12);
      float evW2  = __shfl(ev, hW2);
      float evX   = __shfl(ev, hX);

      float sc = w0*S*ea.x;
      accSC += evSC*sc;
      if(lane<16){
        float vd3 = V[lane*3]*ea.y + V[lane*3+1]*ea.z + V[lane*3+2]*ea.w;
        float sc2 = (float)wr[144+lane]*vd3*inv_s3;
        accSC2 += evSC2*sc2;
      }
      {
        uchar2 rd = sT3[lane];
        float e1d = (rd.y==0)?ea.y:((rd.y==1)?ea.z:ea.w);
        accW1_0 += evW10*WS1[rd.x]*e1d;
      }
      {
        uchar2 rd = sT3[64+lane];
        float e1d = (rd.y==0)?ea.y:((rd.y==1)?ea.z:ea.w);
        accW1_1 += evW11*WS1[rd.x]*e1d;
      }
      {
        uchar2 rd = sT3[128+lane];
        float e1d = (rd.y==0)?ea.y:((rd.y==1)?ea.z:ea.w);
        accW1_2 += evW12*WS1[rd.x]*e1d;
      }
      if(lane<48){
        uchar2 rd = sT3[lane];
        int k = rd.x, d = rd.y;
        accW2 += evW2*(float)wr[128+k]*ea.x*Vl;
        int d1 = (d==2)?0:(d+1);
        int d2 = (d==0)?2:(d-1);
        float e1d2 = (d2==0)?ea.y:((d2==1)?ea.z:ea.w);
        float e1d1 = (d1==0)?ea.y:((d1==1)?ea.z:ea.w);
        float cr = V[3*k+d1]*e1d2 - V[3*k+d2]*e1d1;
        accX += evX*(float)wr[160+k]*cr*inv_s2;
      }
    }

    // ---- normalize + write agg row ----
    float dnSC  = __shfl(den, hSC)  + 1e-9f;
    float dnSC2 = __shfl(den, hSC2) + 1e-9f;
    float dnW10 = __shfl(den, hW10) + 1e-9f;
    float dnW11 = __shfl(den, hW11) + 1e-9f;
    float dnW12 = __shfl(den, hW12) + 1e-9f;
    float dnW2  = __shfl(den, hW2)  + 1e-9f;
    float dnX   = __shfl(den, hX)   + 1e-9f;
    float* ar = agg + (size_t)n*VROW;
    ar[lane]       = accW1_0/dnW10;
    ar[64+lane]    = accW1_1/dnW11;
    ar[128+lane]   = accW1_2/dnW12;
    if(lane<48){
      ar[192+lane] = accW2/dnW2;
      ar[240+lane] = accX/dnX;
    }
    ar[288+lane]   = accSC/dnSC;
    if(lane<16) ar[352+lane] = accSC2/dnSC2;
  }
}

// ---------- K5: output projections (64 nodes / block) ----------
__global__ __launch_bounds__(256) void k_proj(
  const float* __restrict__ agg,
  const float* __restrict__ pws, const float* __restrict__ pbs,
  const float* __restrict__ pwv, float* __restrict__ out, int N)
{
  __shared__ float sWs[80*64];
  __shared__ float sWv[96*16];
  __shared__ ushort sBv[96];
  __shared__ float sA[4][VROW];
  int t=threadIdx.x, wid=t>>6, lane=t&63;
  for(int i=t;i<80*64;i+=256) sWs[i]=pws[i];
  for(int i=t;i<96*16;i+=256) sWv[i]=pwv[i];
  for(int c=t;c<96;c+=256){
    int base = (c<64) ? c*3 : (c<80) ? 192+(c-64)*3 : 240+(c-80)*3;
    sBv[c] = (ushort)base;
  }
  __syncthreads();
  for(int itn=0; itn<16; ++itn){
    int n = blockIdx.x*64 + itn*4 + wid;
    if(n>=N) continue;
    const float* arow = agg + (size_t)n*VROW;
    float* A = sA[wid];
    for(int j=lane;j<VROW;j+=64) A[j] = arow[j];
    float o1 = pbs[lane];
    #pragma unroll 8
    for(int i=0;i<80;i++) o1 += A[288+i]*sWs[i*64+lane];
    out[(size_t)n*112+lane]=o1;
    if(lane<48){
      int ee=lane/3, d=lane-ee*3; float o2=0.f;
      #pragma unroll 8
      for(int c=0;c<96;c++) o2 += A[sBv[c]+d]*sWv[c*16+ee];
      out[(size_t)n*112+64+lane]=o2;
    }
  }
}

extern "C" void kernel_launch(void* const* d_in, const int* in_sizes, int n_in,
                              void* d_out, int out_size, void* d_ws, size_t ws_size,
                              hipStream_t stream)
{
  const int N = in_sizes[0]/112;
  const int E = in_sizes[1];
  const float* ni    = (const float*)d_in[0];
  const int*   esrc  = (const int*)d_in[1];
  const int*   edst  = (const int*)d_in[2];
  const float* eattr = (const float*)d_in[3];
  const float* escal = (const float*)d_in[4];
  const float* wss   = (const float*)d_in[5];
  const float* wsv   = (const float*)d_in[6];
  const float* wds   = (const float*)d_in[7];
  const float* wdv   = (const float*)d_in[8];
  const float* rw1   = (const float*)d_in[9];
  const float* rb1   = (const float*)d_in[10];
  const float* rw2   = (const float*)d_in[11];
  const float* rb2   = (const float*)d_in[12];
  const float* adot  = (const float*)d_in[13];
  const float* pws   = (const float*)d_in[14];
  const float* pbs   = (const float*)d_in[15];
  const float* pwv   = (const float*)d_in[16];
  float* out = (float*)d_out;

  char* ws = (char*)d_ws;
  size_t off = 0;
  auto alloc = [&](size_t bytes)->void*{
    void* p = ws + off;
    off = (off + bytes + 255) & ~(size_t)255;
    return p;
  };
  float*    xs_s  = (float*)   alloc((size_t)N*64*4);
  float*    xs_d  = (float*)   alloc((size_t)N*64*4);
  float*    xv_s  = (float*)   alloc((size_t)N*48*4);
  float*    xv_d  = (float*)   alloc((size_t)N*48*4);
  _Float16* wbuf  = (_Float16*)alloc((size_t)E*WST*2);
  float*    agg   = (float*)   alloc((size_t)N*VROW*4);
  float*    alphaC= (float*)   alloc((size_t)E*8*4);
  int*      pos_of= (int*)     alloc((size_t)E*4);
  int*      srcC  = (int*)     alloc((size_t)E*4);
  float4*   eaC   = (float4*)  alloc((size_t)E*16);
  int*      deg   = (int*)     alloc((size_t)N*4);
  int*      offs  = (int*)     alloc((size_t)(N+1)*4);
  int*      cur   = (int*)     alloc((size_t)N*4);

  hipMemsetAsync(deg, 0, (size_t)N*4, stream);

  k_node<<<(N+63)/64, 256, 0, stream>>>(ni, wss, wsv, wds, wdv, xs_s, xs_d, xv_s, xv_d, N);
  k_deg<<<(E+255)/256, 256, 0, stream>>>(edst, deg, E);
  k_scan<<<1, 256, 0, stream>>>(deg, offs, cur, N);
  k_fill<<<(E+255)/256, 256, 0, stream>>>(esrc, edst, eattr, cur, pos_of, srcC, eaC, E);

  k_mlp<<<512, 256, 0, stream>>>(escal, rw1, rb1, rw2, rb2, pos_of, wbuf, E);

  k_fuse<<<(N+3)/4, 256, 0, stream>>>(offs, srcC, eaC, wbuf, adot,
        xs_s, xs_d, xv_s, xv_d, alphaC, agg, N);

  k_proj<<<(N+63)/64, 256, 0, stream>>>(agg, pws, pbs, pwv, out, N);
}

// Round 7
// 776.589 us; speedup vs baseline: 1.1711x; 1.1711x over previous
//
#include <hip/hip_runtime.h>
#include <hip/hip_bf16.h>

#define WST 184   // wbuf row stride in f16 (176 + 8 pad)
#define CST 232   // compact row stride in f16: [WS1 64|V 48|W2E 16|W4X 16|SC 80|ea float4]

typedef __attribute__((ext_vector_type(8))) short bf16x8;
typedef __attribute__((ext_vector_type(4))) float f32x4;

__device__ inline ushort f2bf(float f){
  union { __hip_bfloat16 b; ushort u; } v;
  v.b = __float2bfloat16(f);
  return v.u;
}

// ---------- K1: node transforms (64 nodes / block) ----------
__global__ __launch_bounds__(256) void k_node(
  const float* __restrict__ ni,
  const float* __restrict__ wss, const float* __restrict__ wsv,
  const float* __restrict__ wds, const float* __restrict__ wdv,
  float* __restrict__ xs_s, float* __restrict__ xs_d,
  float* __restrict__ xv_s, float* __restrict__ xv_d, int N)
{
  __shared__ float sW0[64*64], sW1[64*64];
  __shared__ float sV0[256], sV1[256];
  __shared__ float sRow[4][112];
  int t = threadIdx.x, wid = t>>6, lane = t&63;
  for(int i=t;i<4096;i+=256){ sW0[i]=wss[i]; sW1[i]=wds[i]; }
  if(t<256){ sV0[t]=wsv[t]; sV1[t]=wdv[t]; }
  __syncthreads();
  for(int itn=0; itn<16; ++itn){
    int node = blockIdx.x*64 + itn*4 + wid;
    if(node>=N) continue;
    const float* row = ni + (size_t)node*112;
    if(lane<56) ((float2*)sRow[wid])[lane] = ((const float2*)row)[lane];
    float* r = sRow[wid];
    float a0=0.f, a1=0.f;
    #pragma unroll 8
    for(int k=0;k<64;k++){ float x=r[k]; a0+=x*sW0[k*64+lane]; a1+=x*sW1[k*64+lane]; }
    xs_s[(size_t)node*64+lane]=a0; xs_d[(size_t)node*64+lane]=a1;
    if(lane<48){
      int e_=lane/3, d_=lane-e_*3; float b0=0.f, b1=0.f;
      #pragma unroll
      for(int c=0;c<16;c++){ float x=r[64+c*3+d_]; b0+=x*sV0[c*16+e_]; b1+=x*sV1[c*16+e_]; }
      xv_s[(size_t)node*48+lane]=b0; xv_d[(size_t)node*48+lane]=b1;
    }
  }
}

// ---------- CSR build ----------
__global__ void k_deg(const int* __restrict__ edst, int* __restrict__ deg, int E){
  int e = blockIdx.x*256 + threadIdx.x;
  if(e<E) atomicAdd(&deg[edst[e]], 1);
}

// hierarchical scan: part (exclusive within block) into cur, block sums into bsum
__global__ __launch_bounds__(256) void k_scan1(
  const int* __restrict__ deg, int* __restrict__ cur, int* __restrict__ bsum, int N)
{
  __shared__ int sb[256];
  int t = threadIdx.x, i = blockIdx.x*256 + t;
  int x = (i<N) ? deg[i] : 0;
  sb[t]=x; __syncthreads();
  int v=x;
  #pragma unroll
  for(int o=1;o<256;o<<=1){
    int u=(t>=o)?sb[t-o]:0; __syncthreads();
    v+=u; sb[t]=v; __syncthreads();
  }
  if(i<N) cur[i]=v-x;
  if(t==255) bsum[blockIdx.x]=v;
}

__global__ __launch_bounds__(256) void k_scan2(
  int* __restrict__ bsum, int* __restrict__ offs, int N, int nb)
{
  __shared__ int sb[256];
  int t = threadIdx.x;
  int x = (t<nb) ? bsum[t] : 0;
  sb[t]=x; __syncthreads();
  int v=x;
  #pragma unroll
  for(int o=1;o<256;o<<=1){
    int u=(t>=o)?sb[t-o]:0; __syncthreads();
    v+=u; sb[t]=v; __syncthreads();
  }
  if(t<nb) bsum[t]=v-x;
  if(t==nb-1) offs[N]=v;
}

__global__ void k_scan3(const int* __restrict__ bsum,
                        int* __restrict__ offs, int* __restrict__ cur, int N)
{
  int i = blockIdx.x*256 + threadIdx.x;
  if(i<N){ int v = cur[i] + bsum[blockIdx.x]; offs[i]=v; cur[i]=v; }
}

__global__ void k_fill(const int* __restrict__ edst, int* __restrict__ cur,
                       int* __restrict__ pos_of, int E){
  int e = blockIdx.x*256 + threadIdx.x;
  if(e<E) pos_of[e] = atomicAdd(&cur[edst[e]], 1);
}

// ---------- K2: radial MLP (MFMA), contiguous wbuf writes ----------
__global__ __launch_bounds__(256) void k_mlp(
  const float* __restrict__ escal,
  const float* __restrict__ w1, const float* __restrict__ b1,
  const float* __restrict__ w2, const float* __restrict__ b2,
  _Float16* __restrict__ wbuf, int E)
{
  __shared__ __align__(16) ushort sW1t[64*136];
  __shared__ __align__(16) ushort sW2t[176*72];
  __shared__ __align__(16) ushort ubuf[4][16*WST];
  int t = threadIdx.x, wid = t>>6, lane = t&63;
  int r16 = lane&15, g = lane>>4;

  for(int i=t;i<128*64;i+=256){ int k=i>>6, n=i&63; sW1t[n*136+k]=f2bf(w1[i]); }
  for(int i=t;i<64*176;i+=256){ int k=i/176, n=i-k*176; sW2t[n*72+k]=f2bf(w2[i]); }
  __syncthreads();

  float b1v[4], b2v[11];
  #pragma unroll
  for(int nt=0;nt<4;nt++) b1v[nt]=b1[nt*16+r16];
  #pragma unroll
  for(int s=0;s<11;s++) b2v[s]=b2[s*16+r16];

  ushort* ub = ubuf[wid];
  _Float16* wsb = (_Float16*)ub;

  int ntiles = (E+15)>>4;
  int nw = gridDim.x*4;

  for(int wt = blockIdx.x*4+wid; wt < ntiles; wt += nw){
    int ebase = wt*16;
    int erow = ebase + r16; if(erow >= E) erow = E-1;

    f32x4 acc[4];
    #pragma unroll
    for(int nt=0;nt<4;nt++) acc[nt]=(f32x4){0,0,0,0};
    #pragma unroll
    for(int ks=0;ks<4;ks++){
      const float* p = escal + (size_t)erow*128 + ks*32 + g*8;
      float4 va = *(const float4*)p;
      float4 vb = *(const float4*)(p+4);
      bf16x8 af;
      af[0]=(short)f2bf(va.x); af[1]=(short)f2bf(va.y);
      af[2]=(short)f2bf(va.z); af[3]=(short)f2bf(va.w);
      af[4]=(short)f2bf(vb.x); af[5]=(short)f2bf(vb.y);
      af[6]=(short)f2bf(vb.z); af[7]=(short)f2bf(vb.w);
      #pragma unroll
      for(int nt=0;nt<4;nt++){
        bf16x8 bf = *(const bf16x8*)&sW1t[(nt*16+r16)*136 + ks*32 + g*8];
        acc[nt] = __builtin_amdgcn_mfma_f32_16x16x32_bf16(af,bf,acc[nt],0,0,0);
      }
    }

    #pragma unroll
    for(int nt=0;nt<4;nt++)
      #pragma unroll
      for(int q=0;q<4;q++) acc[nt][q] += b1v[nt];
    #pragma unroll
    for(int q=0;q<4;q++){
      float s = acc[0][q]+acc[1][q]+acc[2][q]+acc[3][q];
      float ss = acc[0][q]*acc[0][q]+acc[1][q]*acc[1][q]+acc[2][q]*acc[2][q]+acc[3][q]*acc[3][q];
      #pragma unroll
      for(int o=1;o<16;o<<=1){ s += __shfl_xor(s,o); ss += __shfl_xor(ss,o); }
      float m = s*(1.f/64.f);
      float var = ss*(1.f/64.f) - m*m;
      float inv = rsqrtf(var + 1e-5f);
      int rr = g*4+q;
      #pragma unroll
      for(int nt=0;nt<4;nt++){
        float xn = (acc[nt][q]-m)*inv;
        float h = xn/(1.f+__expf(-xn));
        ub[rr*72 + nt*16 + r16] = f2bf(h);
      }
    }

    bf16x8 af2[2];
    af2[0] = *(const bf16x8*)&ub[r16*72 + 0*32 + g*8];
    af2[1] = *(const bf16x8*)&ub[r16*72 + 1*32 + g*8];
    f32x4 c2[11];
    #pragma unroll
    for(int s=0;s<11;s++) c2[s]=(f32x4){0,0,0,0};
    #pragma unroll
    for(int ks=0;ks<2;ks++){
      #pragma unroll
      for(int s=0;s<11;s++){
        bf16x8 bf = *(const bf16x8*)&sW2t[(s*16+r16)*72 + ks*32 + g*8];
        c2[s] = __builtin_amdgcn_mfma_f32_16x16x32_bf16(af2[ks],bf,c2[s],0,0,0);
      }
    }
    #pragma unroll
    for(int s=0;s<11;s++){
      int col = s*16 + r16;
      #pragma unroll
      for(int q=0;q<4;q++){
        wsb[(g*4+q)*WST + col] = (_Float16)(c2[s][q] + b2v[s]);
      }
    }
    int rows = E - ebase; if(rows > 16) rows = 16;
    int nf4 = rows*(WST/8);
    float4* dst = (float4*)(wbuf + (size_t)ebase*WST);
    const float4* srcv = (const float4*)ub;
    for(int i=lane; i<nf4; i+=64) dst[i] = srcv[i];
  }
}

// ---------- K3: geometric phase -> compact rows + alpha (CSR slots) ----------
__global__ __launch_bounds__(256) void k_geo(
  const int* __restrict__ esrc, const int* __restrict__ edst,
  const float* __restrict__ eattr, const _Float16* __restrict__ wbuf,
  const float* __restrict__ adot,
  const float* __restrict__ xs_s, const float* __restrict__ xs_d,
  const float* __restrict__ xv_s, const float* __restrict__ xv_d,
  const int* __restrict__ pos_of,
  _Float16* __restrict__ cbuf, float* __restrict__ alphaC, int E)
{
  __shared__ float sAdot[80];
  __shared__ float sV[4][48];
  __shared__ float sP[4][80];
  int t = threadIdx.x, wid = t>>6, lane = t&63;
  if(t<80) sAdot[t]=adot[t];
  __syncthreads();

  float* V = sV[wid];
  float* P = sP[wid];
  int nw = gridDim.x*4;
  const float inv_s3 = 0.5773502691896258f, inv_s2 = 0.7071067811865475f;

  for(int e = blockIdx.x*4+wid; e < E; e += nw){
    int p = pos_of[e], si = esrc[e], di = edst[e];
    float4 ea = *(const float4*)&eattr[(size_t)e*4];
    const _Float16* wr = wbuf + (size_t)e*WST;
    float S = xs_s[(size_t)si*64+lane] + xs_d[(size_t)di*64+lane];
    float Vl = 0.f;
    if(lane<48){ Vl = xv_s[(size_t)si*48+lane] + xv_d[(size_t)di*48+lane]; V[lane]=Vl; }
    float w0 = (float)wr[lane];
    float w1v = (float)wr[64+lane];
    _Float16* cr = cbuf + (size_t)p*CST;
    cr[lane] = (_Float16)(w1v*S);
    if(lane<48) cr[64+lane] = (_Float16)Vl;
    if(lane<16){
      cr[112+lane] = (_Float16)((float)wr[128+lane]*ea.x);
      cr[128+lane] = (_Float16)((float)wr[160+lane]*inv_s2);
    }
    float sc = w0*S*ea.x;
    cr[144+lane] = (_Float16)sc;
    float sg = 1.f/(1.f+__expf(-sc));
    P[lane] = sc*(0.2f + 0.8f*sg)*sAdot[lane];
    if(lane<16){
      float vd3 = V[lane*3]*ea.y + V[lane*3+1]*ea.z + V[lane*3+2]*ea.w;
      float sc2 = (float)wr[144+lane]*vd3*inv_s3;
      cr[208+lane] = (_Float16)sc2;
      float sg2 = 1.f/(1.f+__expf(-sc2));
      P[64+lane] = sc2*(0.2f + 0.8f*sg2)*sAdot[64+lane];
    }
    if(lane<8){
      float a = P[lane*10];
      #pragma unroll
      for(int c=1;c<10;c++) a += P[lane*10+c];
      alphaC[(size_t)p*8+lane] = a;
    }
    if(lane==0) *(float4*)((char*)cr + 448) = ea;   // e0,e1x,e1y,e1z
  }
}

// ---------- K4: softmax + aggregation + fused projections (wave per node) ----------
__global__ __launch_bounds__(256) void k_agg(
  const int* __restrict__ offs, const float* __restrict__ alphaC,
  const _Float16* __restrict__ cbuf,
  const float* __restrict__ pws, const float* __restrict__ pbs,
  const float* __restrict__ pwv, float* __restrict__ out, int N)
{
  __shared__ float sWs[80*64];
  __shared__ float sWv[96*16];
  __shared__ ushort sBv[96];
  __shared__ float sVa[4][288];
  __shared__ float sSa[4][80];
  int t=threadIdx.x, wid=t>>6, lane=t&63;
  for(int i=t;i<80*64;i+=256) sWs[i]=pws[i];
  for(int i=t;i<96*16;i+=256) sWv[i]=pwv[i];
  for(int c=t;c<96;c+=256){
    int base = (c<64) ? c*3 : (c<80) ? 192+(c-64)*3 : 240+(c-80)*3;
    sBv[c] = (ushort)base;
  }
  __syncthreads();

  float* Va = sVa[wid];
  float* Sa = sSa[wid];

  // static per-lane indices
  int l3 = lane/3;
  int d  = lane - l3*3;
  int k3 = l3*3;
  int d1 = (d==2)?0:d+1;
  int d2 = (d==0)?2:d-1;
  int hW1 = lane/12;            // w1s channel = lane
  int hW2 = (64+l3)/12;         // w2v channel = 64+k
  int hX  = (80+l3)/12;         // cross channel = 80+k
  int hSC = lane/10;            // sc index = lane
  int hSC2= (64+lane)/10;       // sc2 index = 64+lane (lane<16)
  int h8 = lane&7;

  int nw4 = gridDim.x*4;
  for(int n = blockIdx.x*4+wid; n < N; n += nw4){
    int s0 = offs[n], s1 = offs[n+1];

    // pass 1: per-head max over alphaC
    float mx = -1e30f;
    for(int b = s0 + (lane>>3); b < s1; b += 8)
      mx = fmaxf(mx, alphaC[(size_t)b*8 + h8]);
    mx = fmaxf(mx, __shfl_xor(mx, 8));
    mx = fmaxf(mx, __shfl_xor(mx, 16));
    mx = fmaxf(mx, __shfl_xor(mx, 32));

    // pass 2: exp + weighted accumulate from compact rows
    float den = 0.f;
    float aW1x=0.f,aW1y=0.f,aW1z=0.f,aW2=0.f,aX=0.f,aSC=0.f,aSC2=0.f;
    for(int b=s0; b<s1; ++b){
      const _Float16* cr = cbuf + (size_t)b*CST;
      float ev = 0.f;
      if(lane<8){ ev = __expf(alphaC[(size_t)b*8+lane] - mx); den += ev; }
      float ws1 = (float)cr[lane];
      float Vl  = (lane<48) ? (float)cr[64+lane]  : 0.f;
      float w2e = (lane<16) ? (float)cr[112+lane] : 0.f;
      float w4x = (lane<16) ? (float)cr[128+lane] : 0.f;
      float scA = (float)cr[144+lane];
      float scB = (lane<16) ? (float)cr[208+lane] : 0.f;
      float4 ea = *(const float4*)((const char*)cr + 448);

      float evW1 = __shfl(ev, hW1);
      float evW2 = __shfl(ev, hW2);
      float evX  = __shfl(ev, hX);
      float evSC = __shfl(ev, hSC);
      float evS2 = __shfl(ev, hSC2);

      float t1 = evW1*ws1;
      aW1x += t1*ea.y; aW1y += t1*ea.z; aW1z += t1*ea.w;

      float w2ek = __shfl(w2e, l3);
      aW2 += evW2*w2ek*Vl;

      float Vd1 = __shfl(Vl, k3+d1);
      float Vd2 = __shfl(Vl, k3+d2);
      float w4k = __shfl(w4x, l3);
      float e1d1 = (d1==0)?ea.y:((d1==1)?ea.z:ea.w);
      float e1d2 = (d2==0)?ea.y:((d2==1)?ea.z:ea.w);
      aX += evX*w4k*(Vd1*e1d2 - Vd2*e1d1);

      aSC  += evSC*scA;
      aSC2 += evS2*scB;
    }

    float dnW1 = __shfl(den, hW1) + 1e-9f;
    float dnW2 = __shfl(den, hW2) + 1e-9f;
    float dnX  = __shfl(den, hX)  + 1e-9f;
    float dnSC = __shfl(den, hSC) + 1e-9f;
    float dnS2 = __shfl(den, hSC2)+ 1e-9f;

    // stage agg row into per-wave LDS
    Va[lane*3+0] = aW1x/dnW1;
    Va[lane*3+1] = aW1y/dnW1;
    Va[lane*3+2] = aW1z/dnW1;
    if(lane<48){
      Va[192+lane] = aW2/dnW2;
      Va[240+lane] = aX/dnX;
    }
    Sa[lane] = aSC/dnSC;
    if(lane<16) Sa[64+lane] = aSC2/dnS2;

    // fused projections
    float o1 = pbs[lane];
    #pragma unroll 8
    for(int i=0;i<80;i++) o1 += Sa[i]*sWs[i*64+lane];
    out[(size_t)n*112+lane] = o1;
    if(lane<48){
      float o2 = 0.f;
      #pragma unroll 8
      for(int c=0;c<96;c++) o2 += Va[sBv[c]+d]*sWv[c*16+l3];
      out[(size_t)n*112+64+lane] = o2;
    }
  }
}

extern "C" void kernel_launch(void* const* d_in, const int* in_sizes, int n_in,
                              void* d_out, int out_size, void* d_ws, size_t ws_size,
                              hipStream_t stream)
{
  const int N = in_sizes[0]/112;
  const int E = in_sizes[1];
  const float* ni    = (const float*)d_in[0];
  const int*   esrc  = (const int*)d_in[1];
  const int*   edst  = (const int*)d_in[2];
  const float* eattr = (const float*)d_in[3];
  const float* escal = (const float*)d_in[4];
  const float* wss   = (const float*)d_in[5];
  const float* wsv   = (const float*)d_in[6];
  const float* wds   = (const float*)d_in[7];
  const float* wdv   = (const float*)d_in[8];
  const float* rw1   = (const float*)d_in[9];
  const float* rb1   = (const float*)d_in[10];
  const float* rw2   = (const float*)d_in[11];
  const float* rb2   = (const float*)d_in[12];
  const float* adot  = (const float*)d_in[13];
  const float* pws   = (const float*)d_in[14];
  const float* pbs   = (const float*)d_in[15];
  const float* pwv   = (const float*)d_in[16];
  float* out = (float*)d_out;

  char* ws = (char*)d_ws;
  size_t off = 0;
  auto alloc = [&](size_t bytes)->void*{
    void* p = ws + off;
    off = (off + bytes + 255) & ~(size_t)255;
    return p;
  };
  float*    xs_s  = (float*)   alloc((size_t)N*64*4);
  float*    xs_d  = (float*)   alloc((size_t)N*64*4);
  float*    xv_s  = (float*)   alloc((size_t)N*48*4);
  float*    xv_d  = (float*)   alloc((size_t)N*48*4);
  _Float16* wbuf  = (_Float16*)alloc((size_t)E*WST*2);
  _Float16* cbuf  = (_Float16*)alloc((size_t)E*CST*2);
  float*    alphaC= (float*)   alloc((size_t)E*8*4);
  int*      pos_of= (int*)     alloc((size_t)E*4);
  int*      deg   = (int*)     alloc((size_t)N*4);
  int*      offs  = (int*)     alloc((size_t)(N+1)*4);
  int*      cur   = (int*)     alloc((size_t)N*4);
  int*      bsum  = (int*)     alloc(256*4);

  const int nb = (N+255)/256;

  hipMemsetAsync(deg, 0, (size_t)N*4, stream);

  k_node<<<(N+63)/64, 256, 0, stream>>>(ni, wss, wsv, wds, wdv, xs_s, xs_d, xv_s, xv_d, N);
  k_deg<<<(E+255)/256, 256, 0, stream>>>(edst, deg, E);
  k_scan1<<<nb, 256, 0, stream>>>(deg, cur, bsum, N);
  k_scan2<<<1, 256, 0, stream>>>(bsum, offs, N, nb);
  k_scan3<<<nb, 256, 0, stream>>>(bsum, offs, cur, N);
  k_fill<<<(E+255)/256, 256, 0, stream>>>(edst, cur, pos_of, E);

  k_mlp<<<512, 256, 0, stream>>>(escal, rw1, rb1, rw2, rb2, wbuf, E);

  k_geo<<<2048, 256, 0, stream>>>(esrc, edst, eattr, wbuf, adot,
        xs_s, xs_d, xv_s, xv_d, pos_of, cbuf, alphaC, E);

  k_agg<<<2048, 256, 0, stream>>>(offs, alphaC, cbuf, pws, pbs, pwv, out, N);
}

// Round 8
// 716.997 us; speedup vs baseline: 1.2684x; 1.0831x over previous
//
#include <hip/hip_runtime.h>
#include <hip/hip_bf16.h>

#define WST 184   // wbuf row stride in f16 (176 + 8 pad)
#define CROW 264  // cbuf row stride in f16 units (512B lane chunks + 16B ea)

typedef __attribute__((ext_vector_type(8))) short bf16x8;
typedef __attribute__((ext_vector_type(4))) float f32x4;

__device__ inline ushort f2bf(float f){
  union { __hip_bfloat16 b; ushort u; } v;
  v.b = __float2bfloat16(f);
  return v.u;
}
__device__ inline ushort f2h(float f){ _Float16 h=(_Float16)f; ushort u; __builtin_memcpy(&u,&h,2); return u; }
__device__ inline float h2f(ushort u){ _Float16 h; __builtin_memcpy(&h,&u,2); return (float)h; }

// ---------- K1: node transforms (64 nodes / block) ----------
__global__ __launch_bounds__(256) void k_node(
  const float* __restrict__ ni,
  const float* __restrict__ wss, const float* __restrict__ wsv,
  const float* __restrict__ wds, const float* __restrict__ wdv,
  float* __restrict__ xs_s, float* __restrict__ xs_d,
  float* __restrict__ xv_s, float* __restrict__ xv_d, int N)
{
  __shared__ float sW0[64*64], sW1[64*64];
  __shared__ float sV0[256], sV1[256];
  __shared__ float sRow[4][112];
  int t = threadIdx.x, wid = t>>6, lane = t&63;
  for(int i=t;i<4096;i+=256){ sW0[i]=wss[i]; sW1[i]=wds[i]; }
  if(t<256){ sV0[t]=wsv[t]; sV1[t]=wdv[t]; }
  __syncthreads();
  for(int itn=0; itn<16; ++itn){
    int node = blockIdx.x*64 + itn*4 + wid;
    if(node>=N) continue;
    const float* row = ni + (size_t)node*112;
    if(lane<56) ((float2*)sRow[wid])[lane] = ((const float2*)row)[lane];
    float* r = sRow[wid];
    float a0=0.f, a1=0.f;
    #pragma unroll 8
    for(int k=0;k<64;k++){ float x=r[k]; a0+=x*sW0[k*64+lane]; a1+=x*sW1[k*64+lane]; }
    xs_s[(size_t)node*64+lane]=a0; xs_d[(size_t)node*64+lane]=a1;
    if(lane<48){
      int e_=lane/3, d_=lane-e_*3; float b0=0.f, b1=0.f;
      #pragma unroll
      for(int c=0;c<16;c++){ float x=r[64+c*3+d_]; b0+=x*sV0[c*16+e_]; b1+=x*sV1[c*16+e_]; }
      xv_s[(size_t)node*48+lane]=b0; xv_d[(size_t)node*48+lane]=b1;
    }
  }
}

// ---------- CSR build ----------
__global__ void k_deg(const int* __restrict__ edst, int* __restrict__ deg, int E){
  int e = blockIdx.x*256 + threadIdx.x;
  if(e<E) atomicAdd(&deg[edst[e]], 1);
}

__global__ __launch_bounds__(256) void k_scan1(
  const int* __restrict__ deg, int* __restrict__ cur, int* __restrict__ bsum, int N)
{
  __shared__ int sb[256];
  int t = threadIdx.x, i = blockIdx.x*256 + t;
  int x = (i<N) ? deg[i] : 0;
  sb[t]=x; __syncthreads();
  int v=x;
  #pragma unroll
  for(int o=1;o<256;o<<=1){
    int u=(t>=o)?sb[t-o]:0; __syncthreads();
    v+=u; sb[t]=v; __syncthreads();
  }
  if(i<N) cur[i]=v-x;
  if(t==255) bsum[blockIdx.x]=v;
}

__global__ __launch_bounds__(256) void k_scan2(
  int* __restrict__ bsum, int* __restrict__ offs, int N, int nb)
{
  __shared__ int sb[256];
  int t = threadIdx.x;
  int x = (t<nb) ? bsum[t] : 0;
  sb[t]=x; __syncthreads();
  int v=x;
  #pragma unroll
  for(int o=1;o<256;o<<=1){
    int u=(t>=o)?sb[t-o]:0; __syncthreads();
    v+=u; sb[t]=v; __syncthreads();
  }
  if(t<nb) bsum[t]=v-x;
  if(t==nb-1) offs[N]=v;
}

__global__ void k_scan3(const int* __restrict__ bsum,
                        int* __restrict__ offs, int* __restrict__ cur, int N)
{
  int i = blockIdx.x*256 + threadIdx.x;
  if(i<N){ int v = cur[i] + bsum[blockIdx.x]; offs[i]=v; cur[i]=v; }
}

__global__ void k_fill(const int* __restrict__ edst, int* __restrict__ cur,
                       int* __restrict__ pos_of, int E){
  int e = blockIdx.x*256 + threadIdx.x;
  if(e<E) pos_of[e] = atomicAdd(&cur[edst[e]], 1);
}

// ---------- K2: radial MLP (MFMA), contiguous wbuf writes ----------
__global__ __launch_bounds__(256) void k_mlp(
  const float* __restrict__ escal,
  const float* __restrict__ w1, const float* __restrict__ b1,
  const float* __restrict__ w2, const float* __restrict__ b2,
  _Float16* __restrict__ wbuf, int E)
{
  __shared__ __align__(16) ushort sW1t[64*136];
  __shared__ __align__(16) ushort sW2t[176*72];
  __shared__ __align__(16) ushort ubuf[4][16*WST];
  int t = threadIdx.x, wid = t>>6, lane = t&63;
  int r16 = lane&15, g = lane>>4;

  for(int i=t;i<128*64;i+=256){ int k=i>>6, n=i&63; sW1t[n*136+k]=f2bf(w1[i]); }
  for(int i=t;i<64*176;i+=256){ int k=i/176, n=i-k*176; sW2t[n*72+k]=f2bf(w2[i]); }
  __syncthreads();

  float b1v[4], b2v[11];
  #pragma unroll
  for(int nt=0;nt<4;nt++) b1v[nt]=b1[nt*16+r16];
  #pragma unroll
  for(int s=0;s<11;s++) b2v[s]=b2[s*16+r16];

  ushort* ub = ubuf[wid];
  _Float16* wsb = (_Float16*)ub;

  int ntiles = (E+15)>>4;
  int nw = gridDim.x*4;

  for(int wt = blockIdx.x*4+wid; wt < ntiles; wt += nw){
    int ebase = wt*16;
    int erow = ebase + r16; if(erow >= E) erow = E-1;

    f32x4 acc[4];
    #pragma unroll
    for(int nt=0;nt<4;nt++) acc[nt]=(f32x4){0,0,0,0};
    #pragma unroll
    for(int ks=0;ks<4;ks++){
      const float* p = escal + (size_t)erow*128 + ks*32 + g*8;
      float4 va = *(const float4*)p;
      float4 vb = *(const float4*)(p+4);
      bf16x8 af;
      af[0]=(short)f2bf(va.x); af[1]=(short)f2bf(va.y);
      af[2]=(short)f2bf(va.z); af[3]=(short)f2bf(va.w);
      af[4]=(short)f2bf(vb.x); af[5]=(short)f2bf(vb.y);
      af[6]=(short)f2bf(vb.z); af[7]=(short)f2bf(vb.w);
      #pragma unroll
      for(int nt=0;nt<4;nt++){
        bf16x8 bf = *(const bf16x8*)&sW1t[(nt*16+r16)*136 + ks*32 + g*8];
        acc[nt] = __builtin_amdgcn_mfma_f32_16x16x32_bf16(af,bf,acc[nt],0,0,0);
      }
    }

    #pragma unroll
    for(int nt=0;nt<4;nt++)
      #pragma unroll
      for(int q=0;q<4;q++) acc[nt][q] += b1v[nt];
    #pragma unroll
    for(int q=0;q<4;q++){
      float s = acc[0][q]+acc[1][q]+acc[2][q]+acc[3][q];
      float ss = acc[0][q]*acc[0][q]+acc[1][q]*acc[1][q]+acc[2][q]*acc[2][q]+acc[3][q]*acc[3][q];
      #pragma unroll
      for(int o=1;o<16;o<<=1){ s += __shfl_xor(s,o); ss += __shfl_xor(ss,o); }
      float m = s*(1.f/64.f);
      float var = ss*(1.f/64.f) - m*m;
      float inv = rsqrtf(var + 1e-5f);
      int rr = g*4+q;
      #pragma unroll
      for(int nt=0;nt<4;nt++){
        float xn = (acc[nt][q]-m)*inv;
        float h = xn/(1.f+__expf(-xn));
        ub[rr*72 + nt*16 + r16] = f2bf(h);
      }
    }

    bf16x8 af2[2];
    af2[0] = *(const bf16x8*)&ub[r16*72 + 0*32 + g*8];
    af2[1] = *(const bf16x8*)&ub[r16*72 + 1*32 + g*8];
    f32x4 c2[11];
    #pragma unroll
    for(int s=0;s<11;s++) c2[s]=(f32x4){0,0,0,0};
    #pragma unroll
    for(int ks=0;ks<2;ks++){
      #pragma unroll
      for(int s=0;s<11;s++){
        bf16x8 bf = *(const bf16x8*)&sW2t[(s*16+r16)*72 + ks*32 + g*8];
        c2[s] = __builtin_amdgcn_mfma_f32_16x16x32_bf16(af2[ks],bf,c2[s],0,0,0);
      }
    }
    #pragma unroll
    for(int s=0;s<11;s++){
      int col = s*16 + r16;
      #pragma unroll
      for(int q=0;q<4;q++){
        wsb[(g*4+q)*WST + col] = (_Float16)(c2[s][q] + b2v[s]);
      }
    }
    int rows = E - ebase; if(rows > 16) rows = 16;
    int nf4 = rows*(WST/8);
    float4* dst = (float4*)(wbuf + (size_t)ebase*WST);
    const float4* srcv = (const float4*)ub;
    for(int i=lane; i<nf4; i+=64) dst[i] = srcv[i];
  }
}

// ---------- K3: geometric phase -> lane-major compact rows + alpha ----------
__global__ __launch_bounds__(256) void k_geo(
  const int* __restrict__ esrc, const int* __restrict__ edst,
  const float* __restrict__ eattr, const _Float16* __restrict__ wbuf,
  const float* __restrict__ adot,
  const float* __restrict__ xs_s, const float* __restrict__ xs_d,
  const float* __restrict__ xv_s, const float* __restrict__ xv_d,
  const int* __restrict__ pos_of,
  _Float16* __restrict__ cbuf, float* __restrict__ alphaC, int E)
{
  __shared__ float sAdot[80];
  __shared__ float sV[4][48];
  __shared__ float sP[4][80];
  int t = threadIdx.x, wid = t>>6, lane = t&63;
  if(t<80) sAdot[t]=adot[t];
  __syncthreads();

  float* V = sV[wid];
  float* P = sP[wid];
  int nw = gridDim.x*4;
  const float inv_s3 = 0.5773502691896258f, inv_s2 = 0.7071067811865475f;

  for(int e = blockIdx.x*4+wid; e < E; e += nw){
    int p = pos_of[e], si = esrc[e], di = edst[e];
    float4 ea = *(const float4*)&eattr[(size_t)e*4];
    const _Float16* wr = wbuf + (size_t)e*WST;
    float S = xs_s[(size_t)si*64+lane] + xs_d[(size_t)di*64+lane];
    float Vl = 0.f;
    if(lane<48){ Vl = xv_s[(size_t)si*48+lane] + xv_d[(size_t)di*48+lane]; V[lane]=Vl; }
    float w0 = (float)wr[lane];
    float w1v = (float)wr[64+lane];
    float sc = w0*S*ea.x;
    float sg = 1.f/(1.f+__expf(-sc));
    P[lane] = sc*(0.2f + 0.8f*sg)*sAdot[lane];
    float sc2 = 0.f;
    if(lane<16){
      float vd3 = V[lane*3]*ea.y + V[lane*3+1]*ea.z + V[lane*3+2]*ea.w;
      sc2 = (float)wr[144+lane]*vd3*inv_s3;
      float sg2 = 1.f/(1.f+__expf(-sc2));
      P[64+lane] = sc2*(0.2f + 0.8f*sg2)*sAdot[64+lane];
    }
    if(lane<8){
      float a = P[lane*10];
      #pragma unroll
      for(int c=1;c<10;c++) a += P[lane*10+c];
      alphaC[(size_t)p*8+lane] = a;
    }
    // s3 multi-slot: [0,16): scB; [16,32): w2e[lane-16]; [32,48): w4x[lane-32]
    float s3f = sc2;
    if(lane>=16 && lane<32)      s3f = (float)wr[112+lane]*ea.x;
    else if(lane>=32 && lane<48) s3f = (float)wr[128+lane]*inv_s2;
    else if(lane>=48)            s3f = 0.f;
    ushort4 ck;
    ck.x = f2h(w1v*S);
    ck.y = (lane<48) ? f2h(Vl) : (ushort)0;
    ck.z = f2h(sc);
    ck.w = f2h(s3f);
    _Float16* cr = cbuf + (size_t)p*CROW;
    *(ushort4*)(cr + (size_t)lane*4) = ck;
    if(lane==0) *(float4*)((char*)cr + 512) = ea;
  }
}

// ---------- K4: softmax + aggregation + fused projections (wave per node) ----------
#define EDGE_BODY(b, aW1x,aW1y,aW1z,aW2,aX,aSC,aSC2,den) { \
  const _Float16* cr_ = cbuf + (size_t)(b)*CROW; \
  ushort4 ck_ = *(const ushort4*)(cr_ + (size_t)lane*4); \
  float4 ea_ = *(const float4*)((const char*)cr_ + 512); \
  float ws1_ = h2f(ck_.x), Vl_ = h2f(ck_.y), scA_ = h2f(ck_.z), s3_ = h2f(ck_.w); \
  float ev_ = 0.f; \
  if(lane<8){ ev_ = __expf(alphaC[(size_t)(b)*8+lane] - mx); den += ev_; } \
  float evW1_ = __shfl(ev_,hW1), evW2_ = __shfl(ev_,hW2), evX_ = __shfl(ev_,hX); \
  float evSC_ = __shfl(ev_,hSC), evS2_ = __shfl(ev_,hSC2); \
  float w2ek_ = __shfl(s3_, 16+l3), w4k_ = __shfl(s3_, 32+l3); \
  float Vd1_ = __shfl(Vl_, k3+d1), Vd2_ = __shfl(Vl_, k3+d2); \
  float t1_ = evW1_*ws1_; \
  aW1x += t1_*ea_.y; aW1y += t1_*ea_.z; aW1z += t1_*ea_.w; \
  aW2 += evW2_*w2ek_*Vl_; \
  float e1d1_ = (d1==0)?ea_.y:((d1==1)?ea_.z:ea_.w); \
  float e1d2_ = (d2==0)?ea_.y:((d2==1)?ea_.z:ea_.w); \
  aX += evX_*w4k_*(Vd1_*e1d2_ - Vd2_*e1d1_); \
  aSC += evSC_*scA_; aSC2 += evS2_*s3_; }

__global__ __launch_bounds__(256) void k_agg(
  const int* __restrict__ offs, const float* __restrict__ alphaC,
  const _Float16* __restrict__ cbuf,
  const float* __restrict__ pws, const float* __restrict__ pbs,
  const float* __restrict__ pwv, float* __restrict__ out, int N)
{
  __shared__ float sVa[4][288];
  __shared__ float sSa[4][80];
  int t=threadIdx.x, wid=t>>6, lane=t&63;

  float* Va = sVa[wid];
  float* Sa = sSa[wid];

  int l3 = lane/3;
  int d  = lane - l3*3;
  int k3 = l3*3;
  int d1 = (d==2)?0:d+1;
  int d2 = (d==0)?2:d-1;
  int hW1 = lane/12;
  int hW2 = (64+l3)/12;
  int hX  = (80+l3)/12;
  int hSC = lane/10;
  int hSC2= (64+lane)/10;
  int h8 = lane&7;

  int nw4 = gridDim.x*4;
  for(int n = blockIdx.x*4+wid; n < N; n += nw4){
    int s0 = offs[n], s1 = offs[n+1];

    // pass 1: per-head max
    float mx = -1e30f;
    for(int b = s0 + (lane>>3); b < s1; b += 8)
      mx = fmaxf(mx, alphaC[(size_t)b*8 + h8]);
    mx = fmaxf(mx, __shfl_xor(mx, 8));
    mx = fmaxf(mx, __shfl_xor(mx, 16));
    mx = fmaxf(mx, __shfl_xor(mx, 32));

    // pass 2: 2x-unrolled exp + weighted accumulate
    float denA=0.f, aW1xA=0.f,aW1yA=0.f,aW1zA=0.f,aW2A=0.f,aXA=0.f,aSCA=0.f,aSC2A=0.f;
    float denB=0.f, aW1xB=0.f,aW1yB=0.f,aW1zB=0.f,aW2B=0.f,aXB=0.f,aSCB=0.f,aSC2B=0.f;
    int b = s0;
    for(; b+1 < s1; b += 2){
      EDGE_BODY(b,   aW1xA,aW1yA,aW1zA,aW2A,aXA,aSCA,aSC2A,denA)
      EDGE_BODY(b+1, aW1xB,aW1yB,aW1zB,aW2B,aXB,aSCB,aSC2B,denB)
    }
    if(b < s1){
      EDGE_BODY(b, aW1xA,aW1yA,aW1zA,aW2A,aXA,aSCA,aSC2A,denA)
    }
    float den = denA+denB;
    float aW1x=aW1xA+aW1xB, aW1y=aW1yA+aW1yB, aW1z=aW1zA+aW1zB;
    float aW2=aW2A+aW2B, aX=aXA+aXB, aSC=aSCA+aSCB, aSC2=aSC2A+aSC2B;

    float dnW1 = __shfl(den, hW1) + 1e-9f;
    float dnW2 = __shfl(den, hW2) + 1e-9f;
    float dnX  = __shfl(den, hX)  + 1e-9f;
    float dnSC = __shfl(den, hSC) + 1e-9f;
    float dnS2 = __shfl(den, hSC2)+ 1e-9f;

    Va[lane*3+0] = aW1x/dnW1;
    Va[lane*3+1] = aW1y/dnW1;
    Va[lane*3+2] = aW1z/dnW1;
    if(lane<48){
      Va[192+lane] = aW2/dnW2;
      Va[240+lane] = aX/dnX;
    }
    Sa[lane] = aSC/dnSC;
    if(lane<16) Sa[64+lane] = aSC2/dnS2;

    // fused projections (weights straight from global; L1-resident)
    float o1 = pbs[lane];
    #pragma unroll 8
    for(int i=0;i<80;i++) o1 += Sa[i]*pws[i*64+lane];
    out[(size_t)n*112+lane] = o1;
    if(lane<48){
      float o2 = 0.f;
      #pragma unroll 8
      for(int k=0;k<64;k++) o2 += Va[k*3+d]*pwv[k*16+l3];
      #pragma unroll
      for(int k=0;k<16;k++) o2 += Va[192+k*3+d]*pwv[(64+k)*16+l3];
      #pragma unroll
      for(int k=0;k<16;k++) o2 += Va[240+k*3+d]*pwv[(80+k)*16+l3];
      out[(size_t)n*112+64+lane] = o2;
    }
  }
}

extern "C" void kernel_launch(void* const* d_in, const int* in_sizes, int n_in,
                              void* d_out, int out_size, void* d_ws, size_t ws_size,
                              hipStream_t stream)
{
  const int N = in_sizes[0]/112;
  const int E = in_sizes[1];
  const float* ni    = (const float*)d_in[0];
  const int*   esrc  = (const int*)d_in[1];
  const int*   edst  = (const int*)d_in[2];
  const float* eattr = (const float*)d_in[3];
  const float* escal = (const float*)d_in[4];
  const float* wss   = (const float*)d_in[5];
  const float* wsv   = (const float*)d_in[6];
  const float* wds   = (const float*)d_in[7];
  const float* wdv   = (const float*)d_in[8];
  const float* rw1   = (const float*)d_in[9];
  const float* rb1   = (const float*)d_in[10];
  const float* rw2   = (const float*)d_in[11];
  const float* rb2   = (const float*)d_in[12];
  const float* adot  = (const float*)d_in[13];
  const float* pws   = (const float*)d_in[14];
  const float* pbs   = (const float*)d_in[15];
  const float* pwv   = (const float*)d_in[16];
  float* out = (float*)d_out;

  char* ws = (char*)d_ws;
  size_t off = 0;
  auto alloc = [&](size_t bytes)->void*{
    void* p = ws + off;
    off = (off + bytes + 255) & ~(size_t)255;
    return p;
  };
  float*    xs_s  = (float*)   alloc((size_t)N*64*4);
  float*    xs_d  = (float*)   alloc((size_t)N*64*4);
  float*    xv_s  = (float*)   alloc((size_t)N*48*4);
  float*    xv_d  = (float*)   alloc((size_t)N*48*4);
  _Float16* wbuf  = (_Float16*)alloc((size_t)E*WST*2);
  _Float16* cbuf  = (_Float16*)alloc((size_t)E*CROW*2);
  float*    alphaC= (float*)   alloc((size_t)E*8*4);
  int*      pos_of= (int*)     alloc((size_t)E*4);
  int*      deg   = (int*)     alloc((size_t)N*4);
  int*      offs  = (int*)     alloc((size_t)(N+1)*4);
  int*      cur   = (int*)     alloc((size_t)N*4);
  int*      bsum  = (int*)     alloc(256*4);

  const int nb = (N+255)/256;

  hipMemsetAsync(deg, 0, (size_t)N*4, stream);

  k_node<<<(N+63)/64, 256, 0, stream>>>(ni, wss, wsv, wds, wdv, xs_s, xs_d, xv_s, xv_d, N);
  k_deg<<<(E+255)/256, 256, 0, stream>>>(edst, deg, E);
  k_scan1<<<nb, 256, 0, stream>>>(deg, cur, bsum, N);
  k_scan2<<<1, 256, 0, stream>>>(bsum, offs, N, nb);
  k_scan3<<<nb, 256, 0, stream>>>(bsum, offs, cur, N);
  k_fill<<<(E+255)/256, 256, 0, stream>>>(edst, cur, pos_of, E);

  k_mlp<<<512, 256, 0, stream>>>(escal, rw1, rb1, rw2, rb2, wbuf, E);

  k_geo<<<2048, 256, 0, stream>>>(esrc, edst, eattr, wbuf, adot,
        xs_s, xs_d, xv_s, xv_d, pos_of, cbuf, alphaC, E);

  k_agg<<<2048, 256, 0, stream>>>(offs, alphaC, cbuf, pws, pbs, pwv, out, N);
}

// Round 10
// 677.258 us; speedup vs baseline: 1.3428x; 1.0587x over previous
//
#include <hip/hip_runtime.h>
#include <hip/hip_bf16.h>

#define WST 184   // wbuf row stride in f16 (176 + 8 pad)
#define CROW 264  // cbuf row stride in f16 units (512B lane chunks + 16B ea)

typedef __attribute__((ext_vector_type(8))) short bf16x8;
typedef __attribute__((ext_vector_type(4))) float f32x4;

__device__ inline ushort f2bf(float f){
  union { __hip_bfloat16 b; ushort u; } v;
  v.b = __float2bfloat16(f);
  return v.u;
}
__device__ inline ushort f2h(float f){ _Float16 h=(_Float16)f; ushort u; __builtin_memcpy(&u,&h,2); return u; }
__device__ inline float h2f(ushort u){ _Float16 h; __builtin_memcpy(&h,&u,2); return (float)h; }

// ---------- K1: node transforms (64 nodes / block) ----------
__global__ __launch_bounds__(256) void k_node(
  const float* __restrict__ ni,
  const float* __restrict__ wss, const float* __restrict__ wsv,
  const float* __restrict__ wds, const float* __restrict__ wdv,
  float* __restrict__ xs_s, float* __restrict__ xs_d,
  float* __restrict__ xv_s, float* __restrict__ xv_d, int N)
{
  __shared__ float sW0[64*64], sW1[64*64];
  __shared__ float sV0[256], sV1[256];
  __shared__ float sRow[4][112];
  int t = threadIdx.x, wid = t>>6, lane = t&63;
  for(int i=t;i<4096;i+=256){ sW0[i]=wss[i]; sW1[i]=wds[i]; }
  if(t<256){ sV0[t]=wsv[t]; sV1[t]=wdv[t]; }
  __syncthreads();
  for(int itn=0; itn<16; ++itn){
    int node = blockIdx.x*64 + itn*4 + wid;
    if(node>=N) continue;
    const float* row = ni + (size_t)node*112;
    if(lane<56) ((float2*)sRow[wid])[lane] = ((const float2*)row)[lane];
    float* r = sRow[wid];
    float a0=0.f, a1=0.f;
    #pragma unroll 8
    for(int k=0;k<64;k++){ float x=r[k]; a0+=x*sW0[k*64+lane]; a1+=x*sW1[k*64+lane]; }
    xs_s[(size_t)node*64+lane]=a0; xs_d[(size_t)node*64+lane]=a1;
    if(lane<48){
      int e_=lane/3, d_=lane-e_*3; float b0=0.f, b1=0.f;
      #pragma unroll
      for(int c=0;c<16;c++){ float x=r[64+c*3+d_]; b0+=x*sV0[c*16+e_]; b1+=x*sV1[c*16+e_]; }
      xv_s[(size_t)node*48+lane]=b0; xv_d[(size_t)node*48+lane]=b1;
    }
  }
}

// ---------- CSR build ----------
__global__ void k_deg(const int* __restrict__ edst, int* __restrict__ deg, int E){
  int e = blockIdx.x*256 + threadIdx.x;
  if(e<E) atomicAdd(&deg[edst[e]], 1);
}

__global__ __launch_bounds__(256) void k_scan1(
  const int* __restrict__ deg, int* __restrict__ cur, int* __restrict__ bsum, int N)
{
  __shared__ int sb[256];
  int t = threadIdx.x, i = blockIdx.x*256 + t;
  int x = (i<N) ? deg[i] : 0;
  sb[t]=x; __syncthreads();
  int v=x;
  #pragma unroll
  for(int o=1;o<256;o<<=1){
    int u=(t>=o)?sb[t-o]:0; __syncthreads();
    v+=u; sb[t]=v; __syncthreads();
  }
  if(i<N) cur[i]=v-x;
  if(t==255) bsum[blockIdx.x]=v;
}

__global__ __launch_bounds__(256) void k_scan2(
  int* __restrict__ bsum, int* __restrict__ offs, int N, int nb)
{
  __shared__ int sb[256];
  int t = threadIdx.x;
  int x = (t<nb) ? bsum[t] : 0;
  sb[t]=x; __syncthreads();
  int v=x;
  #pragma unroll
  for(int o=1;o<256;o<<=1){
    int u=(t>=o)?sb[t-o]:0; __syncthreads();
    v+=u; sb[t]=v; __syncthreads();
  }
  if(t<nb) bsum[t]=v-x;
  if(t==nb-1) offs[N]=v;
}

__global__ void k_scan3(const int* __restrict__ bsum,
                        int* __restrict__ offs, int* __restrict__ cur, int N)
{
  int i = blockIdx.x*256 + threadIdx.x;
  if(i<N){ int v = cur[i] + bsum[blockIdx.x]; offs[i]=v; cur[i]=v; }
}

__global__ void k_fill(const int* __restrict__ edst, int* __restrict__ cur,
                       int* __restrict__ pos_of, int E){
  int e = blockIdx.x*256 + threadIdx.x;
  if(e<E) pos_of[e] = atomicAdd(&cur[edst[e]], 1);
}

// ---------- K2: radial MLP (MFMA), contiguous wbuf writes ----------
__global__ __launch_bounds__(256) void k_mlp(
  const float* __restrict__ escal,
  const float* __restrict__ w1, const float* __restrict__ b1,
  const float* __restrict__ w2, const float* __restrict__ b2,
  _Float16* __restrict__ wbuf, int E)
{
  __shared__ __align__(16) ushort sW1t[64*136];
  __shared__ __align__(16) ushort sW2t[176*72];
  __shared__ __align__(16) ushort ubuf[4][16*WST];
  int t = threadIdx.x, wid = t>>6, lane = t&63;
  int r16 = lane&15, g = lane>>4;

  for(int i=t;i<128*64;i+=256){ int k=i>>6, n=i&63; sW1t[n*136+k]=f2bf(w1[i]); }
  for(int i=t;i<64*176;i+=256){ int k=i/176, n=i-k*176; sW2t[n*72+k]=f2bf(w2[i]); }
  __syncthreads();

  float b1v[4], b2v[11];
  #pragma unroll
  for(int nt=0;nt<4;nt++) b1v[nt]=b1[nt*16+r16];
  #pragma unroll
  for(int s=0;s<11;s++) b2v[s]=b2[s*16+r16];

  ushort* ub = ubuf[wid];
  _Float16* wsb = (_Float16*)ub;

  int ntiles = (E+15)>>4;
  int nw = gridDim.x*4;

  for(int wt = blockIdx.x*4+wid; wt < ntiles; wt += nw){
    int ebase = wt*16;
    int erow = ebase + r16; if(erow >= E) erow = E-1;

    f32x4 acc[4];
    #pragma unroll
    for(int nt=0;nt<4;nt++) acc[nt]=(f32x4){0,0,0,0};
    #pragma unroll
    for(int ks=0;ks<4;ks++){
      const float* p = escal + (size_t)erow*128 + ks*32 + g*8;
      float4 va = *(const float4*)p;
      float4 vb = *(const float4*)(p+4);
      bf16x8 af;
      af[0]=(short)f2bf(va.x); af[1]=(short)f2bf(va.y);
      af[2]=(short)f2bf(va.z); af[3]=(short)f2bf(va.w);
      af[4]=(short)f2bf(vb.x); af[5]=(short)f2bf(vb.y);
      af[6]=(short)f2bf(vb.z); af[7]=(short)f2bf(vb.w);
      #pragma unroll
      for(int nt=0;nt<4;nt++){
        bf16x8 bf = *(const bf16x8*)&sW1t[(nt*16+r16)*136 + ks*32 + g*8];
        acc[nt] = __builtin_amdgcn_mfma_f32_16x16x32_bf16(af,bf,acc[nt],0,0,0);
      }
    }

    #pragma unroll
    for(int nt=0;nt<4;nt++)
      #pragma unroll
      for(int q=0;q<4;q++) acc[nt][q] += b1v[nt];
    #pragma unroll
    for(int q=0;q<4;q++){
      float s = acc[0][q]+acc[1][q]+acc[2][q]+acc[3][q];
      float ss = acc[0][q]*acc[0][q]+acc[1][q]*acc[1][q]+acc[2][q]*acc[2][q]+acc[3][q]*acc[3][q];
      #pragma unroll
      for(int o=1;o<16;o<<=1){ s += __shfl_xor(s,o); ss += __shfl_xor(ss,o); }
      float m = s*(1.f/64.f);
      float var = ss*(1.f/64.f) - m*m;
      float inv = rsqrtf(var + 1e-5f);
      int rr = g*4+q;
      #pragma unroll
      for(int nt=0;nt<4;nt++){
        float xn = (acc[nt][q]-m)*inv;
        float h = xn/(1.f+__expf(-xn));
        ub[rr*72 + nt*16 + r16] = f2bf(h);
      }
    }

    bf16x8 af2[2];
    af2[0] = *(const bf16x8*)&ub[r16*72 + 0*32 + g*8];
    af2[1] = *(const bf16x8*)&ub[r16*72 + 1*32 + g*8];
    f32x4 c2[11];
    #pragma unroll
    for(int s=0;s<11;s++) c2[s]=(f32x4){0,0,0,0};
    #pragma unroll
    for(int ks=0;ks<2;ks++){
      #pragma unroll
      for(int s=0;s<11;s++){
        bf16x8 bf = *(const bf16x8*)&sW2t[(s*16+r16)*72 + ks*32 + g*8];
        c2[s] = __builtin_amdgcn_mfma_f32_16x16x32_bf16(af2[ks],bf,c2[s],0,0,0);
      }
    }
    #pragma unroll
    for(int s=0;s<11;s++){
      int col = s*16 + r16;
      #pragma unroll
      for(int q=0;q<4;q++){
        wsb[(g*4+q)*WST + col] = (_Float16)(c2[s][q] + b2v[s]);
      }
    }
    int rows = E - ebase; if(rows > 16) rows = 16;
    int nf4 = rows*(WST/8);
    float4* dst = (float4*)(wbuf + (size_t)ebase*WST);
    const float4* srcv = (const float4*)ub;
    for(int i=lane; i<nf4; i+=64) dst[i] = srcv[i];
  }
}

// ---------- K3: geometric phase -> fully pre-multiplied lane-major rows ----------
// ck: x=ws1, y=(lane<48)?w2v_pre:0, z=scA, w=(lane<48)?cross_pre:scB[lane-48]
__global__ __launch_bounds__(256) void k_geo(
  const int* __restrict__ esrc, const int* __restrict__ edst,
  const float* __restrict__ eattr, const _Float16* __restrict__ wbuf,
  const float* __restrict__ adot,
  const float* __restrict__ xs_s, const float* __restrict__ xs_d,
  const float* __restrict__ xv_s, const float* __restrict__ xv_d,
  const int* __restrict__ pos_of,
  _Float16* __restrict__ cbuf, float* __restrict__ alphaC, int E)
{
  __shared__ float sAdot[80];
  __shared__ float sV[4][48];
  __shared__ float sP[4][80];
  int t = threadIdx.x, wid = t>>6, lane = t&63;
  if(t<80) sAdot[t]=adot[t];
  __syncthreads();

  float* V = sV[wid];
  float* P = sP[wid];
  int nw = gridDim.x*4;
  const float inv_s3 = 0.5773502691896258f, inv_s2 = 0.7071067811865475f;

  int l3 = lane/3;            // <16 valid for lane<48
  int d  = lane - l3*3;
  int k3 = l3*3;
  int d1 = (d==2)?0:d+1;
  int d2 = (d==0)?2:d-1;

  for(int e = blockIdx.x*4+wid; e < E; e += nw){
    int p = pos_of[e], si = esrc[e], di = edst[e];
    float4 ea = *(const float4*)&eattr[(size_t)e*4];
    const _Float16* wr = wbuf + (size_t)e*WST;
    float S = xs_s[(size_t)si*64+lane] + xs_d[(size_t)di*64+lane];
    float Vl = 0.f;
    if(lane<48){ Vl = xv_s[(size_t)si*48+lane] + xv_d[(size_t)di*48+lane]; V[lane]=Vl; }
    float w0 = (float)wr[lane];
    float w1v = (float)wr[64+lane];
    float sc = w0*S*ea.x;
    float sg = 1.f/(1.f+__expf(-sc));
    P[lane] = sc*(0.2f + 0.8f*sg)*sAdot[lane];
    float sc2 = 0.f;
    if(lane<16){
      float vd3 = V[lane*3]*ea.y + V[lane*3+1]*ea.z + V[lane*3+2]*ea.w;
      sc2 = (float)wr[144+lane]*vd3*inv_s3;
      float sg2 = 1.f/(1.f+__expf(-sc2));
      P[64+lane] = sc2*(0.2f + 0.8f*sg2)*sAdot[64+lane];
    }
    if(lane<8){
      float a = P[lane*10];
      #pragma unroll
      for(int c=1;c<10;c++) a += P[lane*10+c];
      alphaC[(size_t)p*8+lane] = a;
    }
    // scB broadcast with FULL exec (R8 bug: this shfl sat inside the divergent
    // else-branch, reading exec-inactive source lanes -> undefined values)
    float scBv = __shfl(sc2, lane&15);
    // pre-multiplied value components
    float wslot = scBv;
    if(lane<48){
      float e1d1 = (d1==0)?ea.y:((d1==1)?ea.z:ea.w);
      float e1d2 = (d2==0)?ea.y:((d2==1)?ea.z:ea.w);
      float cr = V[k3+d1]*e1d2 - V[k3+d2]*e1d1;
      wslot = (float)wr[160+l3]*cr*inv_s2;
    }
    float w2v_pre = (lane<48) ? (float)wr[128+l3]*ea.x*Vl : 0.f;
    ushort4 ck;
    ck.x = f2h(w1v*S);
    ck.y = f2h(w2v_pre);
    ck.z = f2h(sc);
    ck.w = f2h(wslot);
    _Float16* cr_ = cbuf + (size_t)p*CROW;
    *(ushort4*)(cr_ + (size_t)lane*4) = ck;
    if(lane==0) *(float4*)((char*)cr_ + 512) = ea;
  }
}

// ---------- K4: softmax + aggregation + fused projections (wave per node) ----------
#define EDGE_PROC(b, ck_, ea_, w1x,w1y,w1z,sc,aa,xx,den) { \
  float ev_ = 0.f; \
  if(lane<8){ ev_ = __expf(alphaC[(size_t)(b)*8+lane] - mx); den += ev_; } \
  float evW1_ = __shfl(ev_,hW1), evSC_ = __shfl(ev_,hSC); \
  float evA_ = __shfl(ev_,hA), evX_ = __shfl(ev_,hX); \
  float ws1_ = h2f(ck_.x), scA_ = h2f(ck_.z), wv_ = h2f(ck_.w); \
  float vA_ = (lane<48) ? h2f(ck_.y) : wv_; \
  float t1_ = evW1_*ws1_; \
  w1x += t1_*ea_.y; w1y += t1_*ea_.z; w1z += t1_*ea_.w; \
  sc += evSC_*scA_; aa += evA_*vA_; xx += evX_*wv_; }

__global__ __launch_bounds__(256) void k_agg(
  const int* __restrict__ offs, const float* __restrict__ alphaC,
  const _Float16* __restrict__ cbuf,
  const float* __restrict__ pws, const float* __restrict__ pbs,
  const float* __restrict__ pwv, float* __restrict__ out, int N)
{
  __shared__ float sVa[4][288];
  __shared__ float sSa[4][80];
  int t=threadIdx.x, wid=t>>6, lane=t&63;

  float* Va = sVa[wid];
  float* Sa = sSa[wid];

  int l3 = lane/3;
  int d  = lane - l3*3;
  int hW1 = lane/12;
  int hX  = (80+l3)/12;
  int hSC = lane/10;
  int hA  = (lane<48) ? (64+l3)/12 : (64+(lane-48))/10;
  int h8 = lane&7;

  int nw4 = gridDim.x*4;
  for(int n = blockIdx.x*4+wid; n < N; n += nw4){
    int s0 = offs[n], s1 = offs[n+1];

    // pass 1: per-head max
    float mx = -1e30f;
    for(int b = s0 + (lane>>3); b < s1; b += 8)
      mx = fmaxf(mx, alphaC[(size_t)b*8 + h8]);
    mx = fmaxf(mx, __shfl_xor(mx, 8));
    mx = fmaxf(mx, __shfl_xor(mx, 16));
    mx = fmaxf(mx, __shfl_xor(mx, 32));

    // pass 2: 4x-unrolled, 2 accumulator sets
    float denA=0.f, w1xA=0.f,w1yA=0.f,w1zA=0.f,scA=0.f,aaA=0.f,xxA=0.f;
    float denB=0.f, w1xB=0.f,w1yB=0.f,w1zB=0.f,scB=0.f,aaB=0.f,xxB=0.f;
    int b = s0;
    for(; b+3 < s1; b += 4){
      const _Float16* c0 = cbuf + (size_t)(b  )*CROW;
      const _Float16* c1 = cbuf + (size_t)(b+1)*CROW;
      const _Float16* c2 = cbuf + (size_t)(b+2)*CROW;
      const _Float16* c3 = cbuf + (size_t)(b+3)*CROW;
      ushort4 k0 = *(const ushort4*)(c0 + (size_t)lane*4);
      ushort4 k1 = *(const ushort4*)(c1 + (size_t)lane*4);
      ushort4 k2 = *(const ushort4*)(c2 + (size_t)lane*4);
      ushort4 k3v= *(const ushort4*)(c3 + (size_t)lane*4);
      float4 e0 = *(const float4*)((const char*)c0 + 512);
      float4 e1 = *(const float4*)((const char*)c1 + 512);
      float4 e2 = *(const float4*)((const char*)c2 + 512);
      float4 e3 = *(const float4*)((const char*)c3 + 512);
      EDGE_PROC(b,   k0, e0, w1xA,w1yA,w1zA,scA,aaA,xxA,denA)
      EDGE_PROC(b+1, k1, e1, w1xB,w1yB,w1zB,scB,aaB,xxB,denB)
      EDGE_PROC(b+2, k2, e2, w1xA,w1yA,w1zA,scA,aaA,xxA,denA)
      EDGE_PROC(b+3, k3v,e3, w1xB,w1yB,w1zB,scB,aaB,xxB,denB)
    }
    for(; b < s1; ++b){
      const _Float16* c0 = cbuf + (size_t)b*CROW;
      ushort4 k0 = *(const ushort4*)(c0 + (size_t)lane*4);
      float4 e0 = *(const float4*)((const char*)c0 + 512);
      EDGE_PROC(b, k0, e0, w1xA,w1yA,w1zA,scA,aaA,xxA,denA)
    }
    float den = denA+denB;
    float w1x=w1xA+w1xB, w1y=w1yA+w1yB, w1z=w1zA+w1zB;
    float sc=scA+scB, aa=aaA+aaB, xx=xxA+xxB;

    float dnW1 = __shfl(den, hW1) + 1e-9f;
    float dnSC = __shfl(den, hSC) + 1e-9f;
    float dnA  = __shfl(den, hA)  + 1e-9f;
    float dnX  = __shfl(den, hX)  + 1e-9f;

    Va[lane*3+0] = w1x/dnW1;
    Va[lane*3+1] = w1y/dnW1;
    Va[lane*3+2] = w1z/dnW1;
    if(lane<48){
      Va[192+lane] = aa/dnA;
      Va[240+lane] = xx/dnX;
    } else {
      Sa[64+(lane-48)] = aa/dnA;
    }
    Sa[lane] = sc/dnSC;

    // fused projections (weights from global; L1-resident)
    float o1 = pbs[lane];
    #pragma unroll 8
    for(int i=0;i<80;i++) o1 += Sa[i]*pws[i*64+lane];
    out[(size_t)n*112+lane] = o1;
    if(lane<48){
      float o2 = 0.f;
      #pragma unroll 8
      for(int k=0;k<64;k++) o2 += Va[k*3+d]*pwv[k*16+l3];
      #pragma unroll
      for(int k=0;k<16;k++) o2 += Va[192+k*3+d]*pwv[(64+k)*16+l3];
      #pragma unroll
      for(int k=0;k<16;k++) o2 += Va[240+k*3+d]*pwv[(80+k)*16+l3];
      out[(size_t)n*112+64+lane] = o2;
    }
  }
}

extern "C" void kernel_launch(void* const* d_in, const int* in_sizes, int n_in,
                              void* d_out, int out_size, void* d_ws, size_t ws_size,
                              hipStream_t stream)
{
  const int N = in_sizes[0]/112;
  const int E = in_sizes[1];
  const float* ni    = (const float*)d_in[0];
  const int*   esrc  = (const int*)d_in[1];
  const int*   edst  = (const int*)d_in[2];
  const float* eattr = (const float*)d_in[3];
  const float* escal = (const float*)d_in[4];
  const float* wss   = (const float*)d_in[5];
  const float* wsv   = (const float*)d_in[6];
  const float* wds   = (const float*)d_in[7];
  const float* wdv   = (const float*)d_in[8];
  const float* rw1   = (const float*)d_in[9];
  const float* rb1   = (const float*)d_in[10];
  const float* rw2   = (const float*)d_in[11];
  const float* rb2   = (const float*)d_in[12];
  const float* adot  = (const float*)d_in[13];
  const float* pws   = (const float*)d_in[14];
  const float* pbs   = (const float*)d_in[15];
  const float* pwv   = (const float*)d_in[16];
  float* out = (float*)d_out;

  char* ws = (char*)d_ws;
  size_t off = 0;
  auto alloc = [&](size_t bytes)->void*{
    void* p = ws + off;
    off = (off + bytes + 255) & ~(size_t)255;
    return p;
  };
  float*    xs_s  = (float*)   alloc((size_t)N*64*4);
  float*    xs_d  = (float*)   alloc((size_t)N*64*4);
  float*    xv_s  = (float*)   alloc((size_t)N*48*4);
  float*    xv_d  = (float*)   alloc((size_t)N*48*4);
  _Float16* wbuf  = (_Float16*)alloc((size_t)E*WST*2);
  _Float16* cbuf  = (_Float16*)alloc((size_t)E*CROW*2);
  float*    alphaC= (float*)   alloc((size_t)E*8*4);
  int*      pos_of= (int*)     alloc((size_t)E*4);
  int*      deg   = (int*)     alloc((size_t)N*4);
  int*      offs  = (int*)     alloc((size_t)(N+1)*4);
  int*      cur   = (int*)     alloc((size_t)N*4);
  int*      bsum  = (int*)     alloc(256*4);

  const int nb = (N+255)/256;

  hipMemsetAsync(deg, 0, (size_t)N*4, stream);

  k_node<<<(N+63)/64, 256, 0, stream>>>(ni, wss, wsv, wds, wdv, xs_s, xs_d, xv_s, xv_d, N);
  k_deg<<<(E+255)/256, 256, 0, stream>>>(edst, deg, E);
  k_scan1<<<nb, 256, 0, stream>>>(deg, cur, bsum, N);
  k_scan2<<<1, 256, 0, stream>>>(bsum, offs, N, nb);
  k_scan3<<<nb, 256, 0, stream>>>(bsum, offs, cur, N);
  k_fill<<<(E+255)/256, 256, 0, stream>>>(edst, cur, pos_of, E);

  k_mlp<<<512, 256, 0, stream>>>(escal, rw1, rb1, rw2, rb2, wbuf, E);

  k_geo<<<2048, 256, 0, stream>>>(esrc, edst, eattr, wbuf, adot,
        xs_s, xs_d, xv_s, xv_d, pos_of, cbuf, alphaC, E);

  k_agg<<<2048, 256, 0, stream>>>(offs, alphaC, cbuf, pws, pbs, pwv, out, N);
}

// Round 11
// 644.223 us; speedup vs baseline: 1.4117x; 1.0513x over previous
//
#include <hip/hip_runtime.h>
#include <hip/hip_bf16.h>

#define WST 184   // wbuf row stride in f16 (176 + 8 pad)
#define CROW 264  // cbuf row stride in f16 units (512B lane chunks + 16B ea)

typedef __attribute__((ext_vector_type(8))) short bf16x8;
typedef __attribute__((ext_vector_type(4))) float f32x4;

__device__ inline ushort f2bf(float f){
  union { __hip_bfloat16 b; ushort u; } v;
  v.b = __float2bfloat16(f);
  return v.u;
}
__device__ inline ushort f2h(float f){ _Float16 h=(_Float16)f; ushort u; __builtin_memcpy(&u,&h,2); return u; }
__device__ inline float h2f(ushort u){ _Float16 h; __builtin_memcpy(&h,&u,2); return (float)h; }

// ---------- K1: node transforms (64 nodes / block) ----------
__global__ __launch_bounds__(256) void k_node(
  const float* __restrict__ ni,
  const float* __restrict__ wss, const float* __restrict__ wsv,
  const float* __restrict__ wds, const float* __restrict__ wdv,
  float* __restrict__ xs_s, float* __restrict__ xs_d,
  float* __restrict__ xv_s, float* __restrict__ xv_d, int N)
{
  __shared__ float sW0[64*64], sW1[64*64];
  __shared__ float sV0[256], sV1[256];
  __shared__ float sRow[4][112];
  int t = threadIdx.x, wid = t>>6, lane = t&63;
  for(int i=t;i<4096;i+=256){ sW0[i]=wss[i]; sW1[i]=wds[i]; }
  if(t<256){ sV0[t]=wsv[t]; sV1[t]=wdv[t]; }
  __syncthreads();
  for(int itn=0; itn<16; ++itn){
    int node = blockIdx.x*64 + itn*4 + wid;
    if(node>=N) continue;
    const float* row = ni + (size_t)node*112;
    if(lane<56) ((float2*)sRow[wid])[lane] = ((const float2*)row)[lane];
    float* r = sRow[wid];
    float a0=0.f, a1=0.f;
    #pragma unroll 8
    for(int k=0;k<64;k++){ float x=r[k]; a0+=x*sW0[k*64+lane]; a1+=x*sW1[k*64+lane]; }
    xs_s[(size_t)node*64+lane]=a0; xs_d[(size_t)node*64+lane]=a1;
    if(lane<48){
      int e_=lane/3, d_=lane-e_*3; float b0=0.f, b1=0.f;
      #pragma unroll
      for(int c=0;c<16;c++){ float x=r[64+c*3+d_]; b0+=x*sV0[c*16+e_]; b1+=x*sV1[c*16+e_]; }
      xv_s[(size_t)node*48+lane]=b0; xv_d[(size_t)node*48+lane]=b1;
    }
  }
}

// ---------- CSR build ----------
__global__ void k_deg(const int* __restrict__ edst, int* __restrict__ deg, int E){
  int e = blockIdx.x*256 + threadIdx.x;
  if(e<E) atomicAdd(&deg[edst[e]], 1);
}

__global__ __launch_bounds__(256) void k_scan1(
  const int* __restrict__ deg, int* __restrict__ cur, int* __restrict__ bsum, int N)
{
  __shared__ int sb[256];
  int t = threadIdx.x, i = blockIdx.x*256 + t;
  int x = (i<N) ? deg[i] : 0;
  sb[t]=x; __syncthreads();
  int v=x;
  #pragma unroll
  for(int o=1;o<256;o<<=1){
    int u=(t>=o)?sb[t-o]:0; __syncthreads();
    v+=u; sb[t]=v; __syncthreads();
  }
  if(i<N) cur[i]=v-x;
  if(t==255) bsum[blockIdx.x]=v;
}

__global__ __launch_bounds__(256) void k_scan2(
  int* __restrict__ bsum, int* __restrict__ offs, int N, int nb)
{
  __shared__ int sb[256];
  int t = threadIdx.x;
  int x = (t<nb) ? bsum[t] : 0;
  sb[t]=x; __syncthreads();
  int v=x;
  #pragma unroll
  for(int o=1;o<256;o<<=1){
    int u=(t>=o)?sb[t-o]:0; __syncthreads();
    v+=u; sb[t]=v; __syncthreads();
  }
  if(t<nb) bsum[t]=v-x;
  if(t==nb-1) offs[N]=v;
}

__global__ void k_scan3(const int* __restrict__ bsum,
                        int* __restrict__ offs, int* __restrict__ cur, int N)
{
  int i = blockIdx.x*256 + threadIdx.x;
  if(i<N){ int v = cur[i] + bsum[blockIdx.x]; offs[i]=v; cur[i]=v; }
}

// fill: pos map + CSR-ordered src/dst/edge_attr
__global__ void k_fill(const int* __restrict__ esrc, const int* __restrict__ edst,
                       const float* __restrict__ eattr, int* __restrict__ cur,
                       int* __restrict__ pos_of, int* __restrict__ srcC,
                       int* __restrict__ dstC, float4* __restrict__ eaC, int E){
  int e = blockIdx.x*256 + threadIdx.x;
  if(e<E){
    int p = atomicAdd(&cur[edst[e]], 1);
    pos_of[e] = p;
    srcC[p] = esrc[e];
    dstC[p] = edst[e];
    eaC[p] = *(const float4*)&eattr[(size_t)e*4];
  }
}

// ---------- K2: radial MLP (MFMA), scatter rows to CSR slots ----------
__global__ __launch_bounds__(256) void k_mlp(
  const float* __restrict__ escal,
  const float* __restrict__ w1, const float* __restrict__ b1,
  const float* __restrict__ w2, const float* __restrict__ b2,
  const int* __restrict__ pos_of,
  _Float16* __restrict__ wbuf, int E)
{
  __shared__ __align__(16) ushort sW1t[64*136];
  __shared__ __align__(16) ushort sW2t[176*72];
  __shared__ __align__(16) ushort ubuf[4][16*WST];
  int t = threadIdx.x, wid = t>>6, lane = t&63;
  int r16 = lane&15, g = lane>>4;

  for(int i=t;i<128*64;i+=256){ int k=i>>6, n=i&63; sW1t[n*136+k]=f2bf(w1[i]); }
  for(int i=t;i<64*176;i+=256){ int k=i/176, n=i-k*176; sW2t[n*72+k]=f2bf(w2[i]); }
  __syncthreads();

  float b1v[4], b2v[11];
  #pragma unroll
  for(int nt=0;nt<4;nt++) b1v[nt]=b1[nt*16+r16];
  #pragma unroll
  for(int s=0;s<11;s++) b2v[s]=b2[s*16+r16];

  ushort* ub = ubuf[wid];
  _Float16* wsb = (_Float16*)ub;

  int ntiles = (E+15)>>4;
  int nw = gridDim.x*4;

  for(int wt = blockIdx.x*4+wid; wt < ntiles; wt += nw){
    int ebase = wt*16;
    int erow = ebase + r16; if(erow >= E) erow = E-1;

    f32x4 acc[4];
    #pragma unroll
    for(int nt=0;nt<4;nt++) acc[nt]=(f32x4){0,0,0,0};
    #pragma unroll
    for(int ks=0;ks<4;ks++){
      const float* p = escal + (size_t)erow*128 + ks*32 + g*8;
      float4 va = *(const float4*)p;
      float4 vb = *(const float4*)(p+4);
      bf16x8 af;
      af[0]=(short)f2bf(va.x); af[1]=(short)f2bf(va.y);
      af[2]=(short)f2bf(va.z); af[3]=(short)f2bf(va.w);
      af[4]=(short)f2bf(vb.x); af[5]=(short)f2bf(vb.y);
      af[6]=(short)f2bf(vb.z); af[7]=(short)f2bf(vb.w);
      #pragma unroll
      for(int nt=0;nt<4;nt++){
        bf16x8 bf = *(const bf16x8*)&sW1t[(nt*16+r16)*136 + ks*32 + g*8];
        acc[nt] = __builtin_amdgcn_mfma_f32_16x16x32_bf16(af,bf,acc[nt],0,0,0);
      }
    }

    #pragma unroll
    for(int nt=0;nt<4;nt++)
      #pragma unroll
      for(int q=0;q<4;q++) acc[nt][q] += b1v[nt];
    #pragma unroll
    for(int q=0;q<4;q++){
      float s = acc[0][q]+acc[1][q]+acc[2][q]+acc[3][q];
      float ss = acc[0][q]*acc[0][q]+acc[1][q]*acc[1][q]+acc[2][q]*acc[2][q]+acc[3][q]*acc[3][q];
      #pragma unroll
      for(int o=1;o<16;o<<=1){ s += __shfl_xor(s,o); ss += __shfl_xor(ss,o); }
      float m = s*(1.f/64.f);
      float var = ss*(1.f/64.f) - m*m;
      float inv = rsqrtf(var + 1e-5f);
      int rr = g*4+q;
      #pragma unroll
      for(int nt=0;nt<4;nt++){
        float xn = (acc[nt][q]-m)*inv;
        float h = xn/(1.f+__expf(-xn));
        ub[rr*72 + nt*16 + r16] = f2bf(h);
      }
    }

    bf16x8 af2[2];
    af2[0] = *(const bf16x8*)&ub[r16*72 + 0*32 + g*8];
    af2[1] = *(const bf16x8*)&ub[r16*72 + 1*32 + g*8];
    f32x4 c2[11];
    #pragma unroll
    for(int s=0;s<11;s++) c2[s]=(f32x4){0,0,0,0};
    #pragma unroll
    for(int ks=0;ks<2;ks++){
      #pragma unroll
      for(int s=0;s<11;s++){
        bf16x8 bf = *(const bf16x8*)&sW2t[(s*16+r16)*72 + ks*32 + g*8];
        c2[s] = __builtin_amdgcn_mfma_f32_16x16x32_bf16(af2[ks],bf,c2[s],0,0,0);
      }
    }
    #pragma unroll
    for(int s=0;s<11;s++){
      int col = s*16 + r16;
      #pragma unroll
      for(int q=0;q<4;q++){
        wsb[(g*4+q)*WST + col] = (_Float16)(c2[s][q] + b2v[s]);
      }
    }
    // scatter rows to CSR slots
    int pv = 0;
    if(lane<16 && ebase+lane < E) pv = pos_of[ebase+lane];
    int rows = E - ebase; if(rows > 16) rows = 16;
    const float4* srcv = (const float4*)ub;
    int tot4 = rows*23;   // WST/8 float4 per row
    for(int i=lane; i<tot4; i+=64){
      int r = i/23, c = i - 23*r;
      int pos = __shfl(pv, r);
      ((float4*)(wbuf + (size_t)pos*WST))[c] = srcv[i];
    }
  }
}

// ---------- K3: geometric phase, CSR-sequential, shuffle-based ----------
// ck: x=ws1, y=(lane<48)?w2v_pre:0, z=scA, w=(lane<48)?cross_pre:scB[lane-48]
__global__ __launch_bounds__(256) void k_geo(
  const int* __restrict__ srcC, const int* __restrict__ dstC,
  const float4* __restrict__ eaC, const _Float16* __restrict__ wbuf,
  const float* __restrict__ adot,
  const float* __restrict__ xs_s, const float* __restrict__ xs_d,
  const float* __restrict__ xv_s, const float* __restrict__ xv_d,
  _Float16* __restrict__ cbuf, float* __restrict__ alphaC, int E)
{
  __shared__ float sAdot[80];
  __shared__ float sP[4][80];
  int t = threadIdx.x, wid = t>>6, lane = t&63;
  if(t<80) sAdot[t]=adot[t];
  __syncthreads();

  float* P = sP[wid];
  int nw = gridDim.x*4;
  const float inv_s3 = 0.5773502691896258f, inv_s2 = 0.7071067811865475f;

  int l3 = lane/3;
  int d  = lane - l3*3;
  int k3 = l3*3;
  int d1 = (d==2)?0:d+1;
  int d2 = (d==0)?2:d-1;
  int l3c = l3&15;                 // clamped for uniform loads
  int sA = (lane*3)&63, sB = (lane*3+1)&63, sC = (lane*3+2)&63;
  int cs1 = (k3+d1)&63, cs2 = (k3+d2)&63;
  int hh5 = (lane>>1)&7, st5 = hh5*10 + (lane&1)*5;
  float adl = sAdot[lane];
  float ad2 = sAdot[64+(lane&15)];

  for(int p = blockIdx.x*4+wid; p < E; p += nw){
    int si = srcC[p], di = dstC[p];
    float4 ea = eaC[p];
    const _Float16* wr = wbuf + (size_t)p*WST;
    float S = xs_s[(size_t)si*64+lane] + xs_d[(size_t)di*64+lane];
    float Vl = (lane<48) ? (xv_s[(size_t)si*48+lane] + xv_d[(size_t)di*48+lane]) : 0.f;
    float w0 = (float)wr[lane];
    float w1v = (float)wr[64+lane];
    float sc = w0*S*ea.x;
    float sg = 1.f/(1.f+__expf(-sc));
    P[lane] = sc*(0.2f + 0.8f*sg)*adl;
    // vd3/sc2 computed branchlessly (valid where used)
    float v0=__shfl(Vl,sA), v1=__shfl(Vl,sB), v2=__shfl(Vl,sC);
    float vd3 = v0*ea.y + v1*ea.z + v2*ea.w;
    float sc2 = (float)wr[144+(lane&15)]*vd3*inv_s3;
    if(lane<16){
      float sg2 = 1.f/(1.f+__expf(-sc2));
      P[64+lane] = sc2*(0.2f + 0.8f*sg2)*ad2;
    }
    // parallel head-sum: each lane sums 5, lanes<8 combine
    float s5 = P[st5] + P[st5+1] + P[st5+2] + P[st5+3] + P[st5+4];
    float aL = __shfl(s5, 2*(lane&7)) + __shfl(s5, 2*(lane&7)+1);
    if(lane<8) alphaC[(size_t)p*8+lane] = aL;
    // scB broadcast (full exec)
    float scBv = __shfl(sc2, lane&15);
    // pre-multiplied value components
    float Vd1 = __shfl(Vl, cs1), Vd2 = __shfl(Vl, cs2);
    float wslot = scBv;
    if(lane<48){
      float e1d1 = (d1==0)?ea.y:((d1==1)?ea.z:ea.w);
      float e1d2 = (d2==0)?ea.y:((d2==1)?ea.z:ea.w);
      float cr = Vd1*e1d2 - Vd2*e1d1;
      wslot = (float)wr[160+l3c]*cr*inv_s2;
    }
    float w2v_pre = (lane<48) ? (float)wr[128+l3c]*ea.x*Vl : 0.f;
    ushort4 ck;
    ck.x = f2h(w1v*S);
    ck.y = f2h(w2v_pre);
    ck.z = f2h(sc);
    ck.w = f2h(wslot);
    _Float16* cr_ = cbuf + (size_t)p*CROW;
    *(ushort4*)(cr_ + (size_t)lane*4) = ck;
    if(lane==0) *(float4*)((char*)cr_ + 512) = ea;
  }
}

// ---------- K4: softmax + aggregation + fused projections (no shuffles/edge) ----------
#define EDGE_PROC(b, ck_, ea_, w1x,w1y,w1z,sc,aa,xx,dW1,dSC,dA,dX) { \
  const float* ar_ = alphaC + (size_t)(b)*8; \
  float evW1_ = __expf(ar_[hW1] - mxW1); \
  float evSC_ = __expf(ar_[hSC] - mxSC); \
  float evA_  = __expf(ar_[hA]  - mxA ); \
  float evX_  = __expf(ar_[hX]  - mxX ); \
  dW1 += evW1_; dSC += evSC_; dA += evA_; dX += evX_; \
  float ws1_ = h2f(ck_.x), scA_ = h2f(ck_.z), wv_ = h2f(ck_.w); \
  float vA_ = (lane<48) ? h2f(ck_.y) : wv_; \
  float t1_ = evW1_*ws1_; \
  w1x += t1_*ea_.y; w1y += t1_*ea_.z; w1z += t1_*ea_.w; \
  sc += evSC_*scA_; aa += evA_*vA_; xx += evX_*wv_; }

__global__ __launch_bounds__(256) void k_agg(
  const int* __restrict__ offs, const float* __restrict__ alphaC,
  const _Float16* __restrict__ cbuf,
  const float* __restrict__ pws, const float* __restrict__ pbs,
  const float* __restrict__ pwv, float* __restrict__ out, int N)
{
  __shared__ float sVa[4][288];
  __shared__ float sSa[4][80];
  int t=threadIdx.x, wid=t>>6, lane=t&63;

  float* Va = sVa[wid];
  float* Sa = sSa[wid];

  int l3 = lane/3;
  int d  = lane - l3*3;
  int hW1 = lane/12;
  int hX  = (80+l3)/12;
  int hSC = lane/10;
  int hA  = (lane<48) ? (64+l3)/12 : (64+(lane-48))/10;
  int h8 = lane&7;

  int nw4 = gridDim.x*4;
  for(int n = blockIdx.x*4+wid; n < N; n += nw4){
    int s0 = offs[n], s1 = offs[n+1];

    // pass 1: per-head max (lane l holds max of head l&7)
    float mx = -1e30f;
    for(int b = s0 + (lane>>3); b < s1; b += 8)
      mx = fmaxf(mx, alphaC[(size_t)b*8 + h8]);
    mx = fmaxf(mx, __shfl_xor(mx, 8));
    mx = fmaxf(mx, __shfl_xor(mx, 16));
    mx = fmaxf(mx, __shfl_xor(mx, 32));
    float mxW1 = __shfl(mx, hW1);
    float mxSC = __shfl(mx, hSC);
    float mxA  = __shfl(mx, hA);
    float mxX  = __shfl(mx, hX);

    // pass 2: 4x-unrolled, 2 accumulator sets, per-lane dens
    float dW1A=0.f,dSCA=0.f,dAA=0.f,dXA=0.f, w1xA=0.f,w1yA=0.f,w1zA=0.f,scA=0.f,aaA=0.f,xxA=0.f;
    float dW1B=0.f,dSCB=0.f,dAB=0.f,dXB=0.f, w1xB=0.f,w1yB=0.f,w1zB=0.f,scB=0.f,aaB=0.f,xxB=0.f;
    int b = s0;
    for(; b+3 < s1; b += 4){
      const _Float16* c0 = cbuf + (size_t)(b  )*CROW;
      const _Float16* c1 = cbuf + (size_t)(b+1)*CROW;
      const _Float16* c2 = cbuf + (size_t)(b+2)*CROW;
      const _Float16* c3 = cbuf + (size_t)(b+3)*CROW;
      ushort4 k0 = *(const ushort4*)(c0 + (size_t)lane*4);
      ushort4 k1 = *(const ushort4*)(c1 + (size_t)lane*4);
      ushort4 k2 = *(const ushort4*)(c2 + (size_t)lane*4);
      ushort4 k3v= *(const ushort4*)(c3 + (size_t)lane*4);
      float4 e0 = *(const float4*)((const char*)c0 + 512);
      float4 e1 = *(const float4*)((const char*)c1 + 512);
      float4 e2 = *(const float4*)((const char*)c2 + 512);
      float4 e3 = *(const float4*)((const char*)c3 + 512);
      EDGE_PROC(b,   k0, e0, w1xA,w1yA,w1zA,scA,aaA,xxA,dW1A,dSCA,dAA,dXA)
      EDGE_PROC(b+1, k1, e1, w1xB,w1yB,w1zB,scB,aaB,xxB,dW1B,dSCB,dAB,dXB)
      EDGE_PROC(b+2, k2, e2, w1xA,w1yA,w1zA,scA,aaA,xxA,dW1A,dSCA,dAA,dXA)
      EDGE_PROC(b+3, k3v,e3, w1xB,w1yB,w1zB,scB,aaB,xxB,dW1B,dSCB,dAB,dXB)
    }
    for(; b < s1; ++b){
      const _Float16* c0 = cbuf + (size_t)b*CROW;
      ushort4 k0 = *(const ushort4*)(c0 + (size_t)lane*4);
      float4 e0 = *(const float4*)((const char*)c0 + 512);
      EDGE_PROC(b, k0, e0, w1xA,w1yA,w1zA,scA,aaA,xxA,dW1A,dSCA,dAA,dXA)
    }
    float dnW1 = dW1A+dW1B + 1e-9f;
    float dnSC = dSCA+dSCB + 1e-9f;
    float dnA  = dAA +dAB  + 1e-9f;
    float dnX  = dXA +dXB  + 1e-9f;
    float w1x=w1xA+w1xB, w1y=w1yA+w1yB, w1z=w1zA+w1zB;
    float sc=scA+scB, aa=aaA+aaB, xx=xxA+xxB;

    Va[lane*3+0] = w1x/dnW1;
    Va[lane*3+1] = w1y/dnW1;
    Va[lane*3+2] = w1z/dnW1;
    if(lane<48){
      Va[192+lane] = aa/dnA;
      Va[240+lane] = xx/dnX;
    } else {
      Sa[64+(lane-48)] = aa/dnA;
    }
    Sa[lane] = sc/dnSC;

    // fused projections (weights from global; L1-resident)
    float o1 = pbs[lane];
    #pragma unroll 8
    for(int i=0;i<80;i++) o1 += Sa[i]*pws[i*64+lane];
    out[(size_t)n*112+lane] = o1;
    if(lane<48){
      float o2 = 0.f;
      #pragma unroll 8
      for(int k=0;k<64;k++) o2 += Va[k*3+d]*pwv[k*16+l3];
      #pragma unroll
      for(int k=0;k<16;k++) o2 += Va[192+k*3+d]*pwv[(64+k)*16+l3];
      #pragma unroll
      for(int k=0;k<16;k++) o2 += Va[240+k*3+d]*pwv[(80+k)*16+l3];
      out[(size_t)n*112+64+lane] = o2;
    }
  }
}

extern "C" void kernel_launch(void* const* d_in, const int* in_sizes, int n_in,
                              void* d_out, int out_size, void* d_ws, size_t ws_size,
                              hipStream_t stream)
{
  const int N = in_sizes[0]/112;
  const int E = in_sizes[1];
  const float* ni    = (const float*)d_in[0];
  const int*   esrc  = (const int*)d_in[1];
  const int*   edst  = (const int*)d_in[2];
  const float* eattr = (const float*)d_in[3];
  const float* escal = (const float*)d_in[4];
  const float* wss   = (const float*)d_in[5];
  const float* wsv   = (const float*)d_in[6];
  const float* wds   = (const float*)d_in[7];
  const float* wdv   = (const float*)d_in[8];
  const float* rw1   = (const float*)d_in[9];
  const float* rb1   = (const float*)d_in[10];
  const float* rw2   = (const float*)d_in[11];
  const float* rb2   = (const float*)d_in[12];
  const float* adot  = (const float*)d_in[13];
  const float* pws   = (const float*)d_in[14];
  const float* pbs   = (const float*)d_in[15];
  const float* pwv   = (const float*)d_in[16];
  float* out = (float*)d_out;

  char* ws = (char*)d_ws;
  size_t off = 0;
  auto alloc = [&](size_t bytes)->void*{
    void* p = ws + off;
    off = (off + bytes + 255) & ~(size_t)255;
    return p;
  };
  float*    xs_s  = (float*)   alloc((size_t)N*64*4);
  float*    xs_d  = (float*)   alloc((size_t)N*64*4);
  float*    xv_s  = (float*)   alloc((size_t)N*48*4);
  float*    xv_d  = (float*)   alloc((size_t)N*48*4);
  _Float16* wbuf  = (_Float16*)alloc((size_t)E*WST*2);
  _Float16* cbuf  = (_Float16*)alloc((size_t)E*CROW*2);
  float*    alphaC= (float*)   alloc((size_t)E*8*4);
  int*      pos_of= (int*)     alloc((size_t)E*4);
  int*      srcC  = (int*)     alloc((size_t)E*4);
  int*      dstC  = (int*)     alloc((size_t)E*4);
  float4*   eaC   = (float4*)  alloc((size_t)E*16);
  int*      deg   = (int*)     alloc((size_t)N*4);
  int*      offs  = (int*)     alloc((size_t)(N+1)*4);
  int*      cur   = (int*)     alloc((size_t)N*4);
  int*      bsum  = (int*)     alloc(256*4);

  const int nb = (N+255)/256;

  hipMemsetAsync(deg, 0, (size_t)N*4, stream);

  k_node<<<(N+63)/64, 256, 0, stream>>>(ni, wss, wsv, wds, wdv, xs_s, xs_d, xv_s, xv_d, N);
  k_deg<<<(E+255)/256, 256, 0, stream>>>(edst, deg, E);
  k_scan1<<<nb, 256, 0, stream>>>(deg, cur, bsum, N);
  k_scan2<<<1, 256, 0, stream>>>(bsum, offs, N, nb);
  k_scan3<<<nb, 256, 0, stream>>>(bsum, offs, cur, N);
  k_fill<<<(E+255)/256, 256, 0, stream>>>(esrc, edst, eattr, cur, pos_of, srcC, dstC, eaC, E);

  k_mlp<<<512, 256, 0, stream>>>(escal, rw1, rb1, rw2, rb2, pos_of, wbuf, E);

  k_geo<<<2048, 256, 0, stream>>>(srcC, dstC, eaC, wbuf, adot,
        xs_s, xs_d, xv_s, xv_d, cbuf, alphaC, E);

  k_agg<<<2048, 256, 0, stream>>>(offs, alphaC, cbuf, pws, pbs, pwv, out, N);
}